// Round 3
// baseline (629.208 us; speedup 1.0000x reference)
//
#include <hip/hip_runtime.h>
#include <math.h>

#define D    256
#define KNN  8

// ---------------------------------------------------------------------------
// Kernel 1: exact replication of the np/f32 reference's 8-NN per query.
// d2 = ||q||^2 - 2 q.p + ||p||^2 with every operation individually
// f32-rounded in the same order numpy/BLAS evaluates it:
//   s_q = (qx^2 + qy^2) + qz^2          (numpy sequential 3-sum)
//   dot = fmaf(qz,pz, fmaf(qy,py, fl(qx*px)))   (BLAS k-ordered FMA)
//   d2  = (s_q - 2*dot) + s_p           (numpy elementwise order)
// Intrinsics (__fmul_rn etc.) forbid compiler re-contraction, so GPU result
// is bit-identical to the CPU reference. Selection: 8 smallest (d2, idx)
// lexicographic == jax.lax.top_k(-d2, 8) tie-breaking.
// One wave per query: per-lane register top-8, then 8-round shuffle merge.
// ---------------------------------------------------------------------------
__global__ __launch_bounds__(64) void knn_kernel(const float* __restrict__ qpos,
                                                 const float* __restrict__ spc,
                                                 int* __restrict__ idx_out, int N)
{
    const int r = blockIdx.x;
    const int l = threadIdx.x;
    const float qx = qpos[3*r+0], qy = qpos[3*r+1], qz = qpos[3*r+2];
    const float sq = __fadd_rn(__fadd_rn(__fmul_rn(qx,qx), __fmul_rn(qy,qy)),
                               __fmul_rn(qz,qz));

    float bd[KNN]; int bi[KNN];
#pragma unroll
    for (int s = 0; s < KNN; ++s) { bd[s] = INFINITY; bi[s] = 0x7fffffff; }
    float wd = INFINITY; int wi = 0x7fffffff;   // current worst slot value

    for (int j = l; j < N; j += 64) {
        const float px = spc[3*j+0], py = spc[3*j+1], pz = spc[3*j+2];
        const float sp = __fadd_rn(__fadd_rn(__fmul_rn(px,px), __fmul_rn(py,py)),
                                   __fmul_rn(pz,pz));
        const float dot = __fmaf_rn(qz, pz, __fmaf_rn(qy, py, __fmul_rn(qx, px)));
        const float d2  = __fadd_rn(__fsub_rn(sq, __fmul_rn(2.0f, dot)), sp);
        if (d2 < wd || (d2 == wd && j < wi)) {
            // find the (lexicographically) worst slot
            int ws = 0; float wdd = bd[0]; int wii = bi[0];
#pragma unroll
            for (int s = 1; s < KNN; ++s) {
                const bool worse = (bd[s] > wdd) || (bd[s] == wdd && bi[s] > wii);
                if (worse) { ws = s; wdd = bd[s]; wii = bi[s]; }
            }
            // replace it (static-indexed, predicated — avoids scratch)
#pragma unroll
            for (int s = 0; s < KNN; ++s) if (s == ws) { bd[s] = d2; bi[s] = j; }
            // recompute worst
            wd = bd[0]; wi = bi[0];
#pragma unroll
            for (int s = 1; s < KNN; ++s) {
                const bool worse = (bd[s] > wd) || (bd[s] == wd && bi[s] > wi);
                if (worse) { wd = bd[s]; wi = bi[s]; }
            }
        }
    }

    // 8-round wave merge, extracting ascending (d2, idx)
#pragma unroll
    for (int round = 0; round < KNN; ++round) {
        float md = bd[0]; int mi = bi[0];
#pragma unroll
        for (int s = 1; s < KNN; ++s) {
            const bool better = (bd[s] < md) || (bd[s] == md && bi[s] < mi);
            if (better) { md = bd[s]; mi = bi[s]; }
        }
        float rd = md; int ri = mi;
#pragma unroll
        for (int o = 32; o; o >>= 1) {
            const float od = __shfl_xor(rd, o);
            const int   oi = __shfl_xor(ri, o);
            const bool better = (od < rd) || (od == rd && oi < ri);
            if (better) { rd = od; ri = oi; }
        }
        if (l == 0) idx_out[r*KNN + round] = ri;
        if (mi == ri) {   // this lane owned the winner: consume its slot
#pragma unroll
            for (int s = 0; s < KNN; ++s)
                if (bi[s] == ri) { bd[s] = INFINITY; bi[s] = 0x7fffffff; }
        }
    }
}

// ---------------------------------------------------------------------------
// Kernel 2/4/5: C[2048,256] = A @ W^T (+ epilogue). 16 rows per block,
// 256 threads (thread = output column), A tile staged in LDS.
// MODE 0: plain store.  MODE 1: C = (A@W^T) * E0 (elementwise).
// MODE 2: C = LayerNorm(A@W^T + E0) * gamma + beta.
// ---------------------------------------------------------------------------
template<int MODE>
__global__ __launch_bounds__(256) void gemm16(const float* __restrict__ A,
                                              const float* __restrict__ W,
                                              float* __restrict__ C,
                                              const float* __restrict__ E0,
                                              const float* __restrict__ gmm,
                                              const float* __restrict__ bta)
{
    __shared__ float a_tile[16][D];   // 16 KiB
    const int r0  = blockIdx.x * 16;
    const int tid = threadIdx.x;

    // stage A tile (coalesced float4)
    {
        const float4* A4 = (const float4*)(A + (size_t)r0 * D);
        float4* T4 = (float4*)(&a_tile[0][0]);
#pragma unroll
        for (int i = 0; i < 4; ++i) T4[tid + i*256] = A4[tid + i*256];
    }
    __syncthreads();

    const int c = tid;
    float acc[16];
#pragma unroll
    for (int r = 0; r < 16; ++r) acc[r] = 0.f;

    const float4* W4 = (const float4*)(W + (size_t)c * D);
    for (int k4 = 0; k4 < D/4; ++k4) {
        const float4 w = W4[k4];
#pragma unroll
        for (int r = 0; r < 16; ++r) {
            const float4 a = *(const float4*)&a_tile[r][k4*4];
            acc[r] = fmaf(a.x, w.x, fmaf(a.y, w.y, fmaf(a.z, w.z, fmaf(a.w, w.w, acc[r]))));
        }
    }

    if (MODE == 0) {
#pragma unroll
        for (int r = 0; r < 16; ++r) C[(size_t)(r0+r)*D + c] = acc[r];
    } else if (MODE == 1) {
#pragma unroll
        for (int r = 0; r < 16; ++r)
            C[(size_t)(r0+r)*D + c] = acc[r] * E0[(size_t)(r0+r)*D + c];
    } else {
        // residual, then per-row LayerNorm
        __syncthreads();
#pragma unroll
        for (int r = 0; r < 16; ++r)
            a_tile[r][c] = acc[r] + E0[(size_t)(r0+r)*D + c];
        __syncthreads();

        const int wave = tid >> 6, lane = tid & 63;
#pragma unroll
        for (int rr = 0; rr < 4; ++rr) {
            const int r = wave*4 + rr;
            const float4 v = *(const float4*)&a_tile[r][lane*4];
            float s  = (v.x + v.y) + (v.z + v.w);
            float s2 = fmaf(v.x, v.x, fmaf(v.y, v.y, fmaf(v.z, v.z, v.w*v.w)));
#pragma unroll
            for (int o = 32; o; o >>= 1) { s += __shfl_xor(s, o); s2 += __shfl_xor(s2, o); }
            const float mu  = s * (1.f/256.f);
            const float var = fmaf(s2, 1.f/256.f, -mu*mu);
            const float rs  = rsqrtf(var + 1e-5f);
            const float4 g = *(const float4*)&gmm[lane*4];
            const float4 b = *(const float4*)&bta[lane*4];
            float4 o4;
            o4.x = (v.x - mu) * rs * g.x + b.x;
            o4.y = (v.y - mu) * rs * g.y + b.y;
            o4.z = (v.z - mu) * rs * g.z + b.z;
            o4.w = (v.w - mu) * rs * g.w + b.w;
            *(float4*)&C[(size_t)(r0+r)*D + lane*4] = o4;
        }
    }
}

// ---------------------------------------------------------------------------
// Kernel 3: per query row — gate = softmax(q@w_k^T + w_b), then
// fbar = sum_j gate_j * inst_feats[idx_j].  One wave per row.
// ---------------------------------------------------------------------------
__global__ __launch_bounds__(64) void gate_fbar(const float* __restrict__ qbuf,
                                                const float* __restrict__ w_k,
                                                const float* __restrict__ w_b,
                                                const float* __restrict__ feats,
                                                const int* __restrict__ idx,
                                                float* __restrict__ fbar)
{
    const int r = blockIdx.x;
    const int l = threadIdx.x;
    const float4 q = *(const float4*)&qbuf[(size_t)r*D + l*4];

    float logit[KNN];
#pragma unroll
    for (int j = 0; j < KNN; ++j) {
        const float4 w = *(const float4*)&w_k[(size_t)j*D + l*4];
        logit[j] = fmaf(q.x, w.x, fmaf(q.y, w.y, fmaf(q.z, w.z, q.w*w.w)));
    }
#pragma unroll
    for (int o = 32; o; o >>= 1) {
#pragma unroll
        for (int j = 0; j < KNN; ++j) logit[j] += __shfl_xor(logit[j], o);
    }
#pragma unroll
    for (int j = 0; j < KNN; ++j) logit[j] += w_b[j];

    float m = logit[0];
#pragma unroll
    for (int j = 1; j < KNN; ++j) m = fmaxf(m, logit[j]);
    float e[KNN]; float ssum = 0.f;
#pragma unroll
    for (int j = 0; j < KNN; ++j) { e[j] = expf(logit[j] - m); ssum += e[j]; }
    const float inv = 1.f / ssum;

    int ids[KNN];
#pragma unroll
    for (int j = 0; j < KNN; ++j) ids[j] = idx[r*KNN + j];

    float4 acc = make_float4(0.f, 0.f, 0.f, 0.f);
#pragma unroll
    for (int j = 0; j < KNN; ++j) {
        const float gj = e[j] * inv;
        const float4 f = *(const float4*)&feats[(size_t)ids[j]*D + l*4];
        acc.x = fmaf(gj, f.x, acc.x);
        acc.y = fmaf(gj, f.y, acc.y);
        acc.z = fmaf(gj, f.z, acc.z);
        acc.w = fmaf(gj, f.w, acc.w);
    }
    *(float4*)&fbar[(size_t)r*D + l*4] = acc;
}

// ---------------------------------------------------------------------------
extern "C" void kernel_launch(void* const* d_in, const int* in_sizes, int n_in,
                              void* d_out, int out_size, void* d_ws, size_t ws_size,
                              hipStream_t stream)
{
    const float* query = (const float*)d_in[0];
    const float* qpos  = (const float*)d_in[1];
    const float* feats = (const float*)d_in[2];
    const float* spc   = (const float*)d_in[3];
    const float* w_q   = (const float*)d_in[4];
    const float* w_v   = (const float*)d_in[5];
    const float* w_o   = (const float*)d_in[6];
    const float* w_k   = (const float*)d_in[7];
    const float* w_b   = (const float*)d_in[8];
    const float* gamma = (const float*)d_in[9];
    const float* beta  = (const float*)d_in[10];

    const int Nq = in_sizes[0] / D;   // 2048
    const int N  = in_sizes[2] / D;   // 50000

    char* ws = (char*)d_ws;
    size_t off = 0;
    int* idx = (int*)(ws + off);
    off += ((size_t)Nq * KNN * sizeof(int) + 255) & ~(size_t)255;
    float* qbuf = (float*)(ws + off); off += (size_t)Nq * D * sizeof(float);
    float* fbar = (float*)(ws + off); off += (size_t)Nq * D * sizeof(float);
    float* wbuf = (float*)(ws + off); off += (size_t)Nq * D * sizeof(float);

    knn_kernel<<<Nq, 64, 0, stream>>>(qpos, spc, idx, N);
    gemm16<0><<<Nq/16, 256, 0, stream>>>(query, w_q, qbuf, nullptr, nullptr, nullptr);
    gate_fbar<<<Nq, 64, 0, stream>>>(qbuf, w_k, w_b, feats, idx, fbar);
    gemm16<1><<<Nq/16, 256, 0, stream>>>(fbar, w_v, wbuf, qbuf, nullptr, nullptr);
    gemm16<2><<<Nq/16, 256, 0, stream>>>(wbuf, w_o, (float*)d_out, query, gamma, beta);
}

// Round 4
// 303.270 us; speedup vs baseline: 2.0747x; 2.0747x over previous
//
#include <hip/hip_runtime.h>
#include <math.h>

#define D       256
#define KNN     8
#define NCHUNK  8

typedef unsigned long long u64;

// key = (f32 bits of d2) << 32 | idx.  d2 >= 0 (true d2 >= ~1e-2 here, f32
// rounding error ~1e-5, so never negative) -> bits monotonic -> single u64
// compare == lexicographic (d2, idx) == lax.top_k(-d2) tie-break order.
__device__ __forceinline__ u64 mkkey(float d2, int j) {
    return ((u64)__float_as_uint(d2) << 32) | (u64)(unsigned)j;
}

// ---------------------------------------------------------------------------
// Pack sp_coords into float4 (x, y, z, ||p||^2), sp rounded exactly like the
// reference's sequential 3-sum so downstream d2 stays bit-identical.
// ---------------------------------------------------------------------------
__global__ __launch_bounds__(256) void pack_pts(const float* __restrict__ spc,
                                                float4* __restrict__ pts, int N)
{
    const int j = blockIdx.x * 256 + threadIdx.x;
    if (j < N) {
        const float px = spc[3*j+0], py = spc[3*j+1], pz = spc[3*j+2];
        const float sp = __fadd_rn(__fadd_rn(__fmul_rn(px,px), __fmul_rn(py,py)),
                                   __fmul_rn(pz,pz));
        pts[j] = make_float4(px, py, pz, sp);
    }
}

// ---------------------------------------------------------------------------
// KNN stage 1: one wave per (query, chunk). Per-lane register top-8 held in
// EIGHT NAMED u64 regs (no arrays -> no scratch spill), sorted ascending;
// insert = guarded cndmask shift chain. Then 8-round wave extract-min gives
// the chunk's exact top-8 (d2,idx) keys.
// d2 replicates the np/BLAS f32 rounding exactly:
//   dot = fmaf(qz,pz, fmaf(qy,py, fl(qx*px)))  (BLAS k-ordered FMA)
//   d2  = (sq - 2*dot) + sp                    (numpy elementwise order)
// ---------------------------------------------------------------------------
__global__ __launch_bounds__(64) void knn_chunk(const float* __restrict__ qpos,
                                                const float4* __restrict__ pts,
                                                u64* __restrict__ cand, int N)
{
    const int q = blockIdx.x;
    const int c = blockIdx.y;
    const int l = threadIdx.x;
    const int per = (N + NCHUNK - 1) / NCHUNK;
    const int j0 = c * per;
    const int j1 = (j0 + per < N) ? (j0 + per) : N;

    const float qx = qpos[3*q+0], qy = qpos[3*q+1], qz = qpos[3*q+2];
    const float sq = __fadd_rn(__fadd_rn(__fmul_rn(qx,qx), __fmul_rn(qy,qy)),
                               __fmul_rn(qz,qz));

    u64 k0 = ~0ull, k1 = ~0ull, k2 = ~0ull, k3 = ~0ull,
        k4 = ~0ull, k5 = ~0ull, k6 = ~0ull, k7 = ~0ull;

    for (int j = j0 + l; j < j1; j += 64) {
        const float4 p = pts[j];
        const float dot = __fmaf_rn(qz, p.z, __fmaf_rn(qy, p.y, __fmul_rn(qx, p.x)));
        const float d2  = __fadd_rn(__fsub_rn(sq, __fmul_rn(2.0f, dot)), p.w);
        const u64 x = mkkey(d2, j);
        if (x < k7) {
            const bool c0 = x < k0, c1 = x < k1, c2 = x < k2, c3 = x < k3,
                       c4 = x < k4, c5 = x < k5, c6 = x < k6;
            k7 = c6 ? k6 : x;
            k6 = c5 ? k5 : (c6 ? x : k6);
            k5 = c4 ? k4 : (c5 ? x : k5);
            k4 = c3 ? k3 : (c4 ? x : k4);
            k3 = c2 ? k2 : (c3 ? x : k3);
            k2 = c1 ? k1 : (c2 ? x : k2);
            k1 = c0 ? k0 : (c1 ? x : k1);
            k0 = c0 ? x  : k0;
        }
    }

    // 8-round wave extract-min (keys are unique: idx embedded)
    u64 mine = ~0ull;
#pragma unroll
    for (int r = 0; r < KNN; ++r) {
        u64 m = k0;
#pragma unroll
        for (int o = 32; o; o >>= 1) {
            const u64 t = __shfl_xor(m, o);
            if (t < m) m = t;
        }
        if (k0 == m) {   // owner pops its sorted list
            k0 = k1; k1 = k2; k2 = k3; k3 = k4; k4 = k5; k5 = k6; k6 = k7;
            k7 = ~0ull;
        }
        if (l == r) mine = m;
    }
    if (l < KNN) cand[((size_t)q * NCHUNK + c) * KNN + l] = mine;
}

// ---------------------------------------------------------------------------
// KNN stage 2: one wave per query merges NCHUNK*8 = 64 candidates (1/lane).
// ---------------------------------------------------------------------------
__global__ __launch_bounds__(64) void knn_merge(const u64* __restrict__ cand,
                                                int* __restrict__ idx_out)
{
    const int q = blockIdx.x, l = threadIdx.x;
    u64 k = cand[(size_t)q * (NCHUNK * KNN) + l];
    u64 mine = ~0ull;
#pragma unroll
    for (int r = 0; r < KNN; ++r) {
        u64 m = k;
#pragma unroll
        for (int o = 32; o; o >>= 1) {
            const u64 t = __shfl_xor(m, o);
            if (t < m) m = t;
        }
        if (k == m) k = ~0ull;
        if (l == r) mine = m;
    }
    if (l < KNN) idx_out[q * KNN + l] = (int)(unsigned)(mine & 0xffffffffu);
}

// ---------------------------------------------------------------------------
// C[2048,256] = A @ W^T (+ epilogue). 16 rows/block, 256 threads.
// MODE 0: plain.  MODE 1: C = (A@W^T) * E0.  MODE 2: LN(A@W^T + E0)*g + b.
// ---------------------------------------------------------------------------
template<int MODE>
__global__ __launch_bounds__(256) void gemm16(const float* __restrict__ A,
                                              const float* __restrict__ W,
                                              float* __restrict__ C,
                                              const float* __restrict__ E0,
                                              const float* __restrict__ gmm,
                                              const float* __restrict__ bta)
{
    __shared__ float a_tile[16][D];
    const int r0  = blockIdx.x * 16;
    const int tid = threadIdx.x;

    {
        const float4* A4 = (const float4*)(A + (size_t)r0 * D);
        float4* T4 = (float4*)(&a_tile[0][0]);
#pragma unroll
        for (int i = 0; i < 4; ++i) T4[tid + i*256] = A4[tid + i*256];
    }
    __syncthreads();

    const int c = tid;
    float acc[16];
#pragma unroll
    for (int r = 0; r < 16; ++r) acc[r] = 0.f;

    const float4* W4 = (const float4*)(W + (size_t)c * D);
    for (int k4 = 0; k4 < D/4; ++k4) {
        const float4 w = W4[k4];
#pragma unroll
        for (int r = 0; r < 16; ++r) {
            const float4 a = *(const float4*)&a_tile[r][k4*4];
            acc[r] = fmaf(a.x, w.x, fmaf(a.y, w.y, fmaf(a.z, w.z, fmaf(a.w, w.w, acc[r]))));
        }
    }

    if (MODE == 0) {
#pragma unroll
        for (int r = 0; r < 16; ++r) C[(size_t)(r0+r)*D + c] = acc[r];
    } else if (MODE == 1) {
#pragma unroll
        for (int r = 0; r < 16; ++r)
            C[(size_t)(r0+r)*D + c] = acc[r] * E0[(size_t)(r0+r)*D + c];
    } else {
        __syncthreads();
#pragma unroll
        for (int r = 0; r < 16; ++r)
            a_tile[r][c] = acc[r] + E0[(size_t)(r0+r)*D + c];
        __syncthreads();

        const int wave = tid >> 6, lane = tid & 63;
#pragma unroll
        for (int rr = 0; rr < 4; ++rr) {
            const int r = wave*4 + rr;
            const float4 v = *(const float4*)&a_tile[r][lane*4];
            float s  = (v.x + v.y) + (v.z + v.w);
            float s2 = fmaf(v.x, v.x, fmaf(v.y, v.y, fmaf(v.z, v.z, v.w*v.w)));
#pragma unroll
            for (int o = 32; o; o >>= 1) { s += __shfl_xor(s, o); s2 += __shfl_xor(s2, o); }
            const float mu  = s * (1.f/256.f);
            const float var = fmaf(s2, 1.f/256.f, -mu*mu);
            const float rs  = rsqrtf(var + 1e-5f);
            const float4 g = *(const float4*)&gmm[lane*4];
            const float4 b = *(const float4*)&bta[lane*4];
            float4 o4;
            o4.x = (v.x - mu) * rs * g.x + b.x;
            o4.y = (v.y - mu) * rs * g.y + b.y;
            o4.z = (v.z - mu) * rs * g.z + b.z;
            o4.w = (v.w - mu) * rs * g.w + b.w;
            *(float4*)&C[(size_t)(r0+r)*D + lane*4] = o4;
        }
    }
}

// ---------------------------------------------------------------------------
// gate = softmax(q@w_k^T + w_b); fbar = sum_j gate_j * inst_feats[idx_j].
// ---------------------------------------------------------------------------
__global__ __launch_bounds__(64) void gate_fbar(const float* __restrict__ qbuf,
                                                const float* __restrict__ w_k,
                                                const float* __restrict__ w_b,
                                                const float* __restrict__ feats,
                                                const int* __restrict__ idx,
                                                float* __restrict__ fbar)
{
    const int r = blockIdx.x;
    const int l = threadIdx.x;
    const float4 q = *(const float4*)&qbuf[(size_t)r*D + l*4];

    float logit[KNN];
#pragma unroll
    for (int j = 0; j < KNN; ++j) {
        const float4 w = *(const float4*)&w_k[(size_t)j*D + l*4];
        logit[j] = fmaf(q.x, w.x, fmaf(q.y, w.y, fmaf(q.z, w.z, q.w*w.w)));
    }
#pragma unroll
    for (int o = 32; o; o >>= 1) {
#pragma unroll
        for (int j = 0; j < KNN; ++j) logit[j] += __shfl_xor(logit[j], o);
    }
#pragma unroll
    for (int j = 0; j < KNN; ++j) logit[j] += w_b[j];

    float m = logit[0];
#pragma unroll
    for (int j = 1; j < KNN; ++j) m = fmaxf(m, logit[j]);
    float e[KNN]; float ssum = 0.f;
#pragma unroll
    for (int j = 0; j < KNN; ++j) { e[j] = expf(logit[j] - m); ssum += e[j]; }
    const float inv = 1.f / ssum;

    int ids[KNN];
#pragma unroll
    for (int j = 0; j < KNN; ++j) ids[j] = idx[r*KNN + j];

    float4 acc = make_float4(0.f, 0.f, 0.f, 0.f);
#pragma unroll
    for (int j = 0; j < KNN; ++j) {
        const float gj = e[j] * inv;
        const float4 f = *(const float4*)&feats[(size_t)ids[j]*D + l*4];
        acc.x = fmaf(gj, f.x, acc.x);
        acc.y = fmaf(gj, f.y, acc.y);
        acc.z = fmaf(gj, f.z, acc.z);
        acc.w = fmaf(gj, f.w, acc.w);
    }
    *(float4*)&fbar[(size_t)r*D + l*4] = acc;
}

// ---------------------------------------------------------------------------
extern "C" void kernel_launch(void* const* d_in, const int* in_sizes, int n_in,
                              void* d_out, int out_size, void* d_ws, size_t ws_size,
                              hipStream_t stream)
{
    const float* query = (const float*)d_in[0];
    const float* qpos  = (const float*)d_in[1];
    const float* feats = (const float*)d_in[2];
    const float* spc   = (const float*)d_in[3];
    const float* w_q   = (const float*)d_in[4];
    const float* w_v   = (const float*)d_in[5];
    const float* w_o   = (const float*)d_in[6];
    const float* w_k   = (const float*)d_in[7];
    const float* w_b   = (const float*)d_in[8];
    const float* gamma = (const float*)d_in[9];
    const float* beta  = (const float*)d_in[10];

    const int Nq = in_sizes[0] / D;   // 2048
    const int N  = in_sizes[2] / D;   // 50000

    char* ws = (char*)d_ws;
    size_t off = 0;
    float4* pts = (float4*)(ws + off);
    off += (((size_t)N * sizeof(float4)) + 255) & ~(size_t)255;
    u64* cand = (u64*)(ws + off);
    off += (((size_t)Nq * NCHUNK * KNN * sizeof(u64)) + 255) & ~(size_t)255;
    int* idx = (int*)(ws + off);
    off += (((size_t)Nq * KNN * sizeof(int)) + 255) & ~(size_t)255;
    float* qbuf = (float*)(ws + off); off += (size_t)Nq * D * sizeof(float);
    float* fbar = (float*)(ws + off); off += (size_t)Nq * D * sizeof(float);
    float* wbuf = (float*)(ws + off); off += (size_t)Nq * D * sizeof(float);

    pack_pts<<<(N + 255)/256, 256, 0, stream>>>(spc, pts, N);
    knn_chunk<<<dim3(Nq, NCHUNK), 64, 0, stream>>>(qpos, pts, cand, N);
    knn_merge<<<Nq, 64, 0, stream>>>(cand, idx);
    gemm16<0><<<Nq/16, 256, 0, stream>>>(query, w_q, qbuf, nullptr, nullptr, nullptr);
    gate_fbar<<<Nq, 64, 0, stream>>>(qbuf, w_k, w_b, feats, idx, fbar);
    gemm16<1><<<Nq/16, 256, 0, stream>>>(fbar, w_v, wbuf, qbuf, nullptr, nullptr);
    gemm16<2><<<Nq/16, 256, 0, stream>>>(wbuf, w_o, (float*)d_out, query, gamma, beta);
}

// Round 5
// 141.811 us; speedup vs baseline: 4.4370x; 2.1386x over previous
//
#include <hip/hip_runtime.h>
#include <math.h>

#define D       256
#define KNN     8
#define G       16           // grid cells per axis
#define NCELL   (G*G*G)
#define CS      0.625f       // cell size = 10/16, exactly representable
#define EPS_D2  2e-3f        // margin >> f32 rounding error of reference d2

typedef unsigned long long u64;

// orderable-float transform: monotonic u32 for any f32 (handles negatives)
__device__ __forceinline__ unsigned enc_f32(float f) {
    unsigned b = __float_as_uint(f);
    return b ^ ((unsigned)(((int)b) >> 31) | 0x80000000u);
}
__device__ __forceinline__ float dec_f32(unsigned t) {
    unsigned m = (unsigned)(((int)t) >> 31);          // 0xFFFFFFFF if t signed-neg (orig >= 0)
    return __uint_as_float(t ^ (0x80000000u | ~m));
}
__device__ __forceinline__ u64 mkkey(float d2, int j) {
    return ((u64)enc_f32(d2) << 32) | (u64)(unsigned)j;
}
__device__ __forceinline__ int cell_of(float x) {
    int c = (int)(x * 1.6f);
    return c < 0 ? 0 : (c > G-1 ? G-1 : c);
}

// ---------------------------------------------------------------------------
// Grid build: histogram -> prefix scan -> scatter (packed x,y,z,idx)
// ---------------------------------------------------------------------------
__global__ __launch_bounds__(256) void grid_hist(const float* __restrict__ spc,
                                                 int* __restrict__ counts, int N)
{
    const int j = blockIdx.x * 256 + threadIdx.x;
    if (j < N) {
        const int cx = cell_of(spc[3*j+0]), cy = cell_of(spc[3*j+1]), cz = cell_of(spc[3*j+2]);
        atomicAdd(&counts[cx | (cy << 4) | (cz << 8)], 1);
    }
}

__global__ __launch_bounds__(1024) void grid_scan(const int* __restrict__ counts,
                                                  int* __restrict__ starts,
                                                  int* __restrict__ cursor)
{
    __shared__ int part[1024];
    const int t = threadIdx.x;
    const int c0 = counts[4*t+0], c1 = counts[4*t+1], c2 = counts[4*t+2], c3 = counts[4*t+3];
    const int s0 = c0, s1 = s0 + c1, s2 = s1 + c2, s3 = s2 + c3;
    part[t] = s3;
    __syncthreads();
    for (int off = 1; off < 1024; off <<= 1) {
        const int v = (t >= off) ? part[t - off] : 0;
        __syncthreads();
        part[t] += v;
        __syncthreads();
    }
    const int excl = (t > 0) ? part[t-1] : 0;
    starts[4*t+0] = excl;        cursor[4*t+0] = excl;
    starts[4*t+1] = excl + s0;   cursor[4*t+1] = excl + s0;
    starts[4*t+2] = excl + s1;   cursor[4*t+2] = excl + s1;
    starts[4*t+3] = excl + s2;   cursor[4*t+3] = excl + s2;
    if (t == 1023) starts[4096] = excl + s3;
}

__global__ __launch_bounds__(256) void grid_scatter(const float* __restrict__ spc,
                                                    int* __restrict__ cursor,
                                                    float4* __restrict__ pts, int N)
{
    const int j = blockIdx.x * 256 + threadIdx.x;
    if (j < N) {
        const float px = spc[3*j+0], py = spc[3*j+1], pz = spc[3*j+2];
        const int cell = cell_of(px) | (cell_of(py) << 4) | (cell_of(pz) << 8);
        const int pos = atomicAdd(&cursor[cell], 1);
        pts[pos] = make_float4(px, py, pz, __int_as_float(j));
    }
}

// ---------------------------------------------------------------------------
// Grid KNN: one wave per query. Expanding Chebyshev rings of cells; lane c
// scans cell c's points serially, keeping a per-lane top-8 of u64 keys
// (bit-exact reference d2). After each ring: destructive wave merge -> global
// top-8, stop when worst8 + eps <= min distance^2 to any unvisited cell.
// Reference-exact d2: dot = fma(qz,pz, fma(qy,py, fl(qx*px)));
//                     d2  = (sq - fl(2*dot)) + sp   (all ops f32-rounded)
// ---------------------------------------------------------------------------
__global__ __launch_bounds__(64) void knn_grid(const float* __restrict__ qpos,
                                               const float4* __restrict__ pts,
                                               const int* __restrict__ starts,
                                               int* __restrict__ idx_out)
{
    const int q = blockIdx.x;
    const int l = threadIdx.x;
    const float qx = qpos[3*q+0], qy = qpos[3*q+1], qz = qpos[3*q+2];
    const float sq = __fadd_rn(__fadd_rn(__fmul_rn(qx,qx), __fmul_rn(qy,qy)),
                               __fmul_rn(qz,qz));
    const int cx = cell_of(qx), cy = cell_of(qy), cz = cell_of(qz);

    u64 k0 = ~0ull, k1 = ~0ull, k2 = ~0ull, k3 = ~0ull,
        k4 = ~0ull, k5 = ~0ull, k6 = ~0ull, k7 = ~0ull;
    u64 mine = ~0ull;

    for (int r = 1; r <= G; ++r) {
        const int w = 2*r + 1, w2 = w*w, ncells = w2*w;
        for (int s = l; s < ncells; s += 64) {
            const int dz = s / w2, rem = s - dz*w2, dy = rem / w, dx = rem - dy*w;
            const int ax = dx - r, ay = dy - r, az = dz - r;
            // interior cells already visited in earlier rings
            const int ch = max(max(abs(ax), abs(ay)), abs(az));
            if (r > 1 && ch < r) continue;
            const int x = cx + ax, y = cy + ay, z = cz + az;
            if (x < 0 || x >= G || y < 0 || y >= G || z < 0 || z >= G) continue;
            const int cell = x | (y << 4) | (z << 8);
            const int st = starts[cell], en = starts[cell+1];
            for (int i = st; i < en; ++i) {
                const float4 p = pts[i];
                const float sp  = __fadd_rn(__fadd_rn(__fmul_rn(p.x,p.x), __fmul_rn(p.y,p.y)),
                                            __fmul_rn(p.z,p.z));
                const float dot = __fmaf_rn(qz, p.z, __fmaf_rn(qy, p.y, __fmul_rn(qx, p.x)));
                const float d2  = __fadd_rn(__fsub_rn(sq, __fmul_rn(2.0f, dot)), sp);
                const u64 xk = mkkey(d2, __float_as_int(p.w));
                if (xk < k7) {
                    const bool c0 = xk < k0, c1 = xk < k1, c2 = xk < k2, c3 = xk < k3,
                               c4 = xk < k4, c5 = xk < k5, c6 = xk < k6;
                    k7 = c6 ? k6 : xk;
                    k6 = c5 ? k5 : (c6 ? xk : k6);
                    k5 = c4 ? k4 : (c5 ? xk : k5);
                    k4 = c3 ? k3 : (c4 ? xk : k4);
                    k3 = c2 ? k2 : (c3 ? xk : k3);
                    k2 = c1 ? k1 : (c2 ? xk : k2);
                    k1 = c0 ? k0 : (c1 ? xk : k1);
                    k0 = c0 ? xk : k0;
                }
            }
        }

        // destructive wave merge: extract global top-8 ascending
        u64 worst = ~0ull;
#pragma unroll
        for (int rd = 0; rd < KNN; ++rd) {
            u64 m = k0;
#pragma unroll
            for (int o = 32; o; o >>= 1) {
                const u64 t = __shfl_xor(m, o);
                if (t < m) m = t;
            }
            if (k0 == m) {   // owner pops its sorted list
                k0 = k1; k1 = k2; k2 = k3; k3 = k4; k4 = k5; k5 = k6; k6 = k7;
                k7 = ~0ull;
            }
            if (l == rd) mine = m;
            if (rd == KNN-1) worst = m;    // wave-uniform
        }

        // stop check: min true distance^2 to any point outside visited block
        const float w8 = dec_f32((unsigned)(worst >> 32));   // NaN if worst==~0 -> never stops
        float dmin = INFINITY;
        if (cx - r > 0)      dmin = fminf(dmin, qx - (float)(cx - r) * CS);
        if (cx + r < G - 1)  dmin = fminf(dmin, (float)(cx + r + 1) * CS - qx);
        if (cy - r > 0)      dmin = fminf(dmin, qy - (float)(cy - r) * CS);
        if (cy + r < G - 1)  dmin = fminf(dmin, (float)(cy + r + 1) * CS - qy);
        if (cz - r > 0)      dmin = fminf(dmin, qz - (float)(cz - r) * CS);
        if (cz + r < G - 1)  dmin = fminf(dmin, (float)(cz + r + 1) * CS - qz);
        if (w8 + EPS_D2 <= dmin * dmin) break;

        // continue: redistribute merged top-8 as new state
        k0 = (l < KNN) ? mine : ~0ull;
        k1 = ~0ull; k2 = ~0ull; k3 = ~0ull; k4 = ~0ull; k5 = ~0ull; k6 = ~0ull; k7 = ~0ull;
    }

    if (l < KNN) idx_out[q*KNN + l] = (int)(unsigned)(mine & 0xffffffffu);
}

// ---------------------------------------------------------------------------
// C[2048,256] = A @ W^T (+ epilogue). 16 rows/block, 256 threads.
// MODE 0: plain.  MODE 1: C = (A@W^T) * E0.  MODE 2: LN(A@W^T + E0)*g + b.
// ---------------------------------------------------------------------------
template<int MODE>
__global__ __launch_bounds__(256) void gemm16(const float* __restrict__ A,
                                              const float* __restrict__ W,
                                              float* __restrict__ C,
                                              const float* __restrict__ E0,
                                              const float* __restrict__ gmm,
                                              const float* __restrict__ bta)
{
    __shared__ float a_tile[16][D];
    const int r0  = blockIdx.x * 16;
    const int tid = threadIdx.x;

    {
        const float4* A4 = (const float4*)(A + (size_t)r0 * D);
        float4* T4 = (float4*)(&a_tile[0][0]);
#pragma unroll
        for (int i = 0; i < 4; ++i) T4[tid + i*256] = A4[tid + i*256];
    }
    __syncthreads();

    const int c = tid;
    float acc[16];
#pragma unroll
    for (int r = 0; r < 16; ++r) acc[r] = 0.f;

    const float4* W4 = (const float4*)(W + (size_t)c * D);
    for (int k4 = 0; k4 < D/4; ++k4) {
        const float4 w = W4[k4];
#pragma unroll
        for (int r = 0; r < 16; ++r) {
            const float4 a = *(const float4*)&a_tile[r][k4*4];
            acc[r] = fmaf(a.x, w.x, fmaf(a.y, w.y, fmaf(a.z, w.z, fmaf(a.w, w.w, acc[r]))));
        }
    }

    if (MODE == 0) {
#pragma unroll
        for (int r = 0; r < 16; ++r) C[(size_t)(r0+r)*D + c] = acc[r];
    } else if (MODE == 1) {
#pragma unroll
        for (int r = 0; r < 16; ++r)
            C[(size_t)(r0+r)*D + c] = acc[r] * E0[(size_t)(r0+r)*D + c];
    } else {
        __syncthreads();
#pragma unroll
        for (int r = 0; r < 16; ++r)
            a_tile[r][c] = acc[r] + E0[(size_t)(r0+r)*D + c];
        __syncthreads();

        const int wave = tid >> 6, lane = tid & 63;
#pragma unroll
        for (int rr = 0; rr < 4; ++rr) {
            const int r = wave*4 + rr;
            const float4 v = *(const float4*)&a_tile[r][lane*4];
            float s  = (v.x + v.y) + (v.z + v.w);
            float s2 = fmaf(v.x, v.x, fmaf(v.y, v.y, fmaf(v.z, v.z, v.w*v.w)));
#pragma unroll
            for (int o = 32; o; o >>= 1) { s += __shfl_xor(s, o); s2 += __shfl_xor(s2, o); }
            const float mu  = s * (1.f/256.f);
            const float var = fmaf(s2, 1.f/256.f, -mu*mu);
            const float rs  = rsqrtf(var + 1e-5f);
            const float4 g = *(const float4*)&gmm[lane*4];
            const float4 b = *(const float4*)&bta[lane*4];
            float4 o4;
            o4.x = (v.x - mu) * rs * g.x + b.x;
            o4.y = (v.y - mu) * rs * g.y + b.y;
            o4.z = (v.z - mu) * rs * g.z + b.z;
            o4.w = (v.w - mu) * rs * g.w + b.w;
            *(float4*)&C[(size_t)(r0+r)*D + lane*4] = o4;
        }
    }
}

// ---------------------------------------------------------------------------
// gate = softmax(q@w_k^T + w_b); fbar = sum_j gate_j * inst_feats[idx_j].
// ---------------------------------------------------------------------------
__global__ __launch_bounds__(64) void gate_fbar(const float* __restrict__ qbuf,
                                                const float* __restrict__ w_k,
                                                const float* __restrict__ w_b,
                                                const float* __restrict__ feats,
                                                const int* __restrict__ idx,
                                                float* __restrict__ fbar)
{
    const int r = blockIdx.x;
    const int l = threadIdx.x;
    const float4 q = *(const float4*)&qbuf[(size_t)r*D + l*4];

    float logit[KNN];
#pragma unroll
    for (int j = 0; j < KNN; ++j) {
        const float4 w = *(const float4*)&w_k[(size_t)j*D + l*4];
        logit[j] = fmaf(q.x, w.x, fmaf(q.y, w.y, fmaf(q.z, w.z, q.w*w.w)));
    }
#pragma unroll
    for (int o = 32; o; o >>= 1) {
#pragma unroll
        for (int j = 0; j < KNN; ++j) logit[j] += __shfl_xor(logit[j], o);
    }
#pragma unroll
    for (int j = 0; j < KNN; ++j) logit[j] += w_b[j];

    float m = logit[0];
#pragma unroll
    for (int j = 1; j < KNN; ++j) m = fmaxf(m, logit[j]);
    float e[KNN]; float ssum = 0.f;
#pragma unroll
    for (int j = 0; j < KNN; ++j) { e[j] = expf(logit[j] - m); ssum += e[j]; }
    const float inv = 1.f / ssum;

    int ids[KNN];
#pragma unroll
    for (int j = 0; j < KNN; ++j) ids[j] = idx[r*KNN + j];

    float4 acc = make_float4(0.f, 0.f, 0.f, 0.f);
#pragma unroll
    for (int j = 0; j < KNN; ++j) {
        const float gj = e[j] * inv;
        const float4 f = *(const float4*)&feats[(size_t)ids[j]*D + l*4];
        acc.x = fmaf(gj, f.x, acc.x);
        acc.y = fmaf(gj, f.y, acc.y);
        acc.z = fmaf(gj, f.z, acc.z);
        acc.w = fmaf(gj, f.w, acc.w);
    }
    *(float4*)&fbar[(size_t)r*D + l*4] = acc;
}

// ---------------------------------------------------------------------------
extern "C" void kernel_launch(void* const* d_in, const int* in_sizes, int n_in,
                              void* d_out, int out_size, void* d_ws, size_t ws_size,
                              hipStream_t stream)
{
    const float* query = (const float*)d_in[0];
    const float* qpos  = (const float*)d_in[1];
    const float* feats = (const float*)d_in[2];
    const float* spc   = (const float*)d_in[3];
    const float* w_q   = (const float*)d_in[4];
    const float* w_v   = (const float*)d_in[5];
    const float* w_o   = (const float*)d_in[6];
    const float* w_k   = (const float*)d_in[7];
    const float* w_b   = (const float*)d_in[8];
    const float* gamma = (const float*)d_in[9];
    const float* beta  = (const float*)d_in[10];

    const int Nq = in_sizes[0] / D;   // 2048
    const int N  = in_sizes[2] / D;   // 50000

    char* ws = (char*)d_ws;
    size_t off = 0;
    int* counts = (int*)(ws + off); off += ((size_t)NCELL * 4 + 255) & ~(size_t)255;
    int* starts = (int*)(ws + off); off += ((size_t)(NCELL+1) * 4 + 255) & ~(size_t)255;
    int* cursor = (int*)(ws + off); off += ((size_t)NCELL * 4 + 255) & ~(size_t)255;
    float4* pts = (float4*)(ws + off); off += ((size_t)N * 16 + 255) & ~(size_t)255;
    int* idx = (int*)(ws + off); off += ((size_t)Nq * KNN * 4 + 255) & ~(size_t)255;
    float* qbuf = (float*)(ws + off); off += (size_t)Nq * D * 4;
    float* fbar = (float*)(ws + off); off += (size_t)Nq * D * 4;
    float* wbuf = (float*)(ws + off); off += (size_t)Nq * D * 4;

    hipMemsetAsync(counts, 0, (size_t)NCELL * 4, stream);
    grid_hist<<<(N + 255)/256, 256, 0, stream>>>(spc, counts, N);
    grid_scan<<<1, 1024, 0, stream>>>(counts, starts, cursor);
    grid_scatter<<<(N + 255)/256, 256, 0, stream>>>(spc, cursor, pts, N);
    knn_grid<<<Nq, 64, 0, stream>>>(qpos, pts, starts, idx);
    gemm16<0><<<Nq/16, 256, 0, stream>>>(query, w_q, qbuf, nullptr, nullptr, nullptr);
    gate_fbar<<<Nq, 64, 0, stream>>>(qbuf, w_k, w_b, feats, idx, fbar);
    gemm16<1><<<Nq/16, 256, 0, stream>>>(fbar, w_v, wbuf, qbuf, nullptr, nullptr);
    gemm16<2><<<Nq/16, 256, 0, stream>>>(wbuf, w_o, (float*)d_out, query, gamma, beta);
}

// Round 6
// 134.319 us; speedup vs baseline: 4.6844x; 1.0558x over previous
//
#include <hip/hip_runtime.h>
#include <math.h>

#define D       256
#define KNN     8
#define G       16           // grid cells per axis
#define NCELL   (G*G*G)
#define CS      0.625f       // cell size = 10/16, exactly representable
#define EPS_D2  2e-3f        // margin >> f32 rounding error of reference d2

typedef unsigned long long u64;

// orderable-float transform: monotonic u32 for any f32 (handles negatives)
__device__ __forceinline__ unsigned enc_f32(float f) {
    unsigned b = __float_as_uint(f);
    return b ^ ((unsigned)(((int)b) >> 31) | 0x80000000u);
}
__device__ __forceinline__ float dec_f32(unsigned t) {
    unsigned m = (unsigned)(((int)t) >> 31);
    return __uint_as_float(t ^ (0x80000000u | ~m));
}
__device__ __forceinline__ u64 mkkey(float d2, int j) {
    return ((u64)enc_f32(d2) << 32) | (u64)(unsigned)j;
}
__device__ __forceinline__ int cell_of(float x) {
    int c = (int)(x * 1.6f);
    return c < 0 ? 0 : (c > G-1 ? G-1 : c);
}

// ---------------------------------------------------------------------------
// Grid build: zero -> histogram -> prefix scan -> scatter (x,y,z,idx packed)
// ---------------------------------------------------------------------------
__global__ __launch_bounds__(256) void zero_counts(int4* __restrict__ c)
{
    c[blockIdx.x * 256 + threadIdx.x] = make_int4(0, 0, 0, 0);
}

__global__ __launch_bounds__(256) void grid_hist(const float* __restrict__ spc,
                                                 int* __restrict__ counts, int N)
{
    const int j = blockIdx.x * 256 + threadIdx.x;
    if (j < N) {
        const int cx = cell_of(spc[3*j+0]), cy = cell_of(spc[3*j+1]), cz = cell_of(spc[3*j+2]);
        atomicAdd(&counts[cx | (cy << 4) | (cz << 8)], 1);
    }
}

__global__ __launch_bounds__(1024) void grid_scan(const int* __restrict__ counts,
                                                  int* __restrict__ starts,
                                                  int* __restrict__ cursor)
{
    __shared__ int part[1024];
    const int t = threadIdx.x;
    const int c0 = counts[4*t+0], c1 = counts[4*t+1], c2 = counts[4*t+2], c3 = counts[4*t+3];
    const int s0 = c0, s1 = s0 + c1, s2 = s1 + c2, s3 = s2 + c3;
    part[t] = s3;
    __syncthreads();
    for (int off = 1; off < 1024; off <<= 1) {
        const int v = (t >= off) ? part[t - off] : 0;
        __syncthreads();
        part[t] += v;
        __syncthreads();
    }
    const int excl = (t > 0) ? part[t-1] : 0;
    starts[4*t+0] = excl;        cursor[4*t+0] = excl;
    starts[4*t+1] = excl + s0;   cursor[4*t+1] = excl + s0;
    starts[4*t+2] = excl + s1;   cursor[4*t+2] = excl + s1;
    starts[4*t+3] = excl + s2;   cursor[4*t+3] = excl + s2;
    if (t == 1023) starts[4096] = excl + s3;
}

__global__ __launch_bounds__(256) void grid_scatter(const float* __restrict__ spc,
                                                    int* __restrict__ cursor,
                                                    float4* __restrict__ pts, int N)
{
    const int j = blockIdx.x * 256 + threadIdx.x;
    if (j < N) {
        const float px = spc[3*j+0], py = spc[3*j+1], pz = spc[3*j+2];
        const int cell = cell_of(px) | (cell_of(py) << 4) | (cell_of(pz) << 8);
        const int pos = atomicAdd(&cursor[cell], 1);
        pts[pos] = make_float4(px, py, pz, __int_as_float(j));
    }
}

// ---------------------------------------------------------------------------
// KNN helpers: per-lane sorted top-8 insert (named regs) + destructive merge
// ---------------------------------------------------------------------------
#define INSERT8(xk)                                                            \
    if ((xk) < k7) {                                                           \
        const bool c0 = (xk) < k0, c1 = (xk) < k1, c2 = (xk) < k2,             \
                   c3 = (xk) < k3, c4 = (xk) < k4, c5 = (xk) < k5,             \
                   c6 = (xk) < k6;                                             \
        k7 = c6 ? k6 : (xk);                                                   \
        k6 = c5 ? k5 : (c6 ? (xk) : k6);                                       \
        k5 = c4 ? k4 : (c5 ? (xk) : k5);                                       \
        k4 = c3 ? k3 : (c4 ? (xk) : k4);                                       \
        k3 = c2 ? k2 : (c3 ? (xk) : k3);                                       \
        k2 = c1 ? k1 : (c2 ? (xk) : k2);                                       \
        k1 = c0 ? k0 : (c1 ? (xk) : k1);                                       \
        k0 = c0 ? (xk) : k0;                                                   \
    }

__device__ __forceinline__ void scan_cell(int cell, const float4* __restrict__ pts,
                                          const int* __restrict__ starts,
                                          float qx, float qy, float qz, float sq,
                                          u64& k0, u64& k1, u64& k2, u64& k3,
                                          u64& k4, u64& k5, u64& k6, u64& k7)
{
    const int st = starts[cell], en = starts[cell+1];
    for (int i = st; i < en; ++i) {
        const float4 p = pts[i];
        const float sp  = __fadd_rn(__fadd_rn(__fmul_rn(p.x,p.x), __fmul_rn(p.y,p.y)),
                                    __fmul_rn(p.z,p.z));
        const float dot = __fmaf_rn(qz, p.z, __fmaf_rn(qy, p.y, __fmul_rn(qx, p.x)));
        const float d2  = __fadd_rn(__fsub_rn(sq, __fmul_rn(2.0f, dot)), sp);
        const u64 xk = mkkey(d2, __float_as_int(p.w));
        INSERT8(xk)
    }
}

__device__ __forceinline__ void wave_merge8(int l, u64& k0, u64& k1, u64& k2, u64& k3,
                                            u64& k4, u64& k5, u64& k6, u64& k7,
                                            u64& mine, u64& worst)
{
#pragma unroll
    for (int rd = 0; rd < KNN; ++rd) {
        u64 m = k0;
#pragma unroll
        for (int o = 32; o; o >>= 1) {
            const u64 t = __shfl_xor(m, o);
            if (t < m) m = t;
        }
        if (k0 == m) {   // owner pops its sorted list
            k0 = k1; k1 = k2; k2 = k3; k3 = k4; k4 = k5; k5 = k6; k6 = k7;
            k7 = ~0ull;
        }
        if (l == rd) mine = m;
        if (rd == KNN-1) worst = m;   // wave-uniform
    }
}

// ---------------------------------------------------------------------------
// KNN: one wave per query, single-shot 4x4x4 cell block (1 cell/lane).
// Block is positioned so the query sits in the middle two cells per axis ->
// min distance to any non-domain face >= 1.5*CS (dmin^2 >= 0.88), while the
// 8-NN radius is ~0.34 (d2 ~ 0.12): stop test passes with huge margin.
// Candidates scored with the BIT-EXACT np/BLAS f32 reference formula; exact
// full-grid fallback kept for the (probability ~1e-15) stop-test failure.
// ---------------------------------------------------------------------------
__global__ __launch_bounds__(64) void knn_grid(const float* __restrict__ qpos,
                                               const float4* __restrict__ pts,
                                               const int* __restrict__ starts,
                                               int* __restrict__ idx_out)
{
    const int q = blockIdx.x;
    const int l = threadIdx.x;
    const float qx = qpos[3*q+0], qy = qpos[3*q+1], qz = qpos[3*q+2];
    const float sq = __fadd_rn(__fadd_rn(__fmul_rn(qx,qx), __fmul_rn(qy,qy)),
                               __fmul_rn(qz,qz));
    const int cx = cell_of(qx), cy = cell_of(qy), cz = cell_of(qz);

    // block start per axis: query lands in cell index 1 or 2 of the block
    auto bstart = [](int c, float coord) {
        const float f = coord * 1.6f - (float)c;      // frac within cell
        int b = c + ((f < 0.5f) ? -2 : -1);
        return b < 0 ? 0 : (b > G-4 ? G-4 : b);
    };
    const int bx = bstart(cx, qx), by = bstart(cy, qy), bz = bstart(cz, qz);

    u64 k0 = ~0ull, k1 = ~0ull, k2 = ~0ull, k3 = ~0ull,
        k4 = ~0ull, k5 = ~0ull, k6 = ~0ull, k7 = ~0ull;

    // lane l -> one cell of the 4x4x4 block
    {
        const int x = bx + (l & 3), y = by + ((l >> 2) & 3), z = bz + (l >> 4);
        scan_cell(x | (y << 4) | (z << 8), pts, starts, qx, qy, qz, sq,
                  k0, k1, k2, k3, k4, k5, k6, k7);
    }

    u64 mine = ~0ull, worst = ~0ull;
    wave_merge8(l, k0, k1, k2, k3, k4, k5, k6, k7, mine, worst);

    // stop test vs nearest unvisited region (domain faces = +inf)
    const float w8 = dec_f32((unsigned)(worst >> 32));   // NaN if <8 cands
    float dmin = INFINITY;
    if (bx > 0)     dmin = fminf(dmin, qx - (float)bx * CS);
    if (bx + 4 < G) dmin = fminf(dmin, (float)(bx + 4) * CS - qx);
    if (by > 0)     dmin = fminf(dmin, qy - (float)by * CS);
    if (by + 4 < G) dmin = fminf(dmin, (float)(by + 4) * CS - qy);
    if (bz > 0)     dmin = fminf(dmin, qz - (float)bz * CS);
    if (bz + 4 < G) dmin = fminf(dmin, (float)(bz + 4) * CS - qz);

    if (!(w8 + EPS_D2 <= dmin * dmin)) {
        // exact fallback: scan every cell outside the block, re-merge
        k0 = (l < KNN) ? mine : ~0ull;
        k1 = ~0ull; k2 = ~0ull; k3 = ~0ull; k4 = ~0ull; k5 = ~0ull; k6 = ~0ull; k7 = ~0ull;
        for (int c = l; c < NCELL; c += 64) {
            const int x = c & 15, y = (c >> 4) & 15, z = c >> 8;
            if (x >= bx && x < bx+4 && y >= by && y < by+4 && z >= bz && z < bz+4) continue;
            scan_cell(c, pts, starts, qx, qy, qz, sq, k0, k1, k2, k3, k4, k5, k6, k7);
        }
        wave_merge8(l, k0, k1, k2, k3, k4, k5, k6, k7, mine, worst);
    }

    if (l < KNN) idx_out[q*KNN + l] = (int)(unsigned)(mine & 0xffffffffu);
}

// ---------------------------------------------------------------------------
// Fused q-GEMM + gate + gather:
//   qbuf = query @ w_q^T                        (16 rows/block, LDS A-tile)
//   gate = softmax(qbuf @ w_k^T + w_b)          (per-row, wave epilogue)
//   fbar = sum_j gate_j * inst_feats[idx_j]
// ---------------------------------------------------------------------------
__global__ __launch_bounds__(256) void gemm_q_gate(const float* __restrict__ A,
                                                   const float* __restrict__ W,
                                                   const float* __restrict__ w_k,
                                                   const float* __restrict__ w_b,
                                                   const float* __restrict__ feats,
                                                   const int* __restrict__ idx,
                                                   float* __restrict__ qbuf,
                                                   float* __restrict__ fbar)
{
    __shared__ float a_tile[16][D];
    const int r0  = blockIdx.x * 16;
    const int tid = threadIdx.x;

    {
        const float4* A4 = (const float4*)(A + (size_t)r0 * D);
        float4* T4 = (float4*)(&a_tile[0][0]);
#pragma unroll
        for (int i = 0; i < 4; ++i) T4[tid + i*256] = A4[tid + i*256];
    }
    __syncthreads();

    const int c = tid;
    float acc[16];
#pragma unroll
    for (int r = 0; r < 16; ++r) acc[r] = 0.f;

    const float4* W4 = (const float4*)(W + (size_t)c * D);
    for (int k4 = 0; k4 < D/4; ++k4) {
        const float4 w = W4[k4];
#pragma unroll
        for (int r = 0; r < 16; ++r) {
            const float4 a = *(const float4*)&a_tile[r][k4*4];
            acc[r] = fmaf(a.x, w.x, fmaf(a.y, w.y, fmaf(a.z, w.z, fmaf(a.w, w.w, acc[r]))));
        }
    }

    // write qbuf + re-stage q tile into LDS for the gate epilogue
#pragma unroll
    for (int r = 0; r < 16; ++r) qbuf[(size_t)(r0+r)*D + c] = acc[r];
    __syncthreads();
#pragma unroll
    for (int r = 0; r < 16; ++r) a_tile[r][c] = acc[r];
    __syncthreads();

    const int wave = tid >> 6, lane = tid & 63;
#pragma unroll
    for (int rr = 0; rr < 4; ++rr) {
        const int r = wave*4 + rr, row = r0 + r;
        const float4 qv = *(const float4*)&a_tile[r][lane*4];

        float logit[KNN];
#pragma unroll
        for (int j = 0; j < KNN; ++j) {
            const float4 w = *(const float4*)&w_k[(size_t)j*D + lane*4];
            logit[j] = fmaf(qv.x, w.x, fmaf(qv.y, w.y, fmaf(qv.z, w.z, qv.w*w.w)));
        }
#pragma unroll
        for (int o = 32; o; o >>= 1) {
#pragma unroll
            for (int j = 0; j < KNN; ++j) logit[j] += __shfl_xor(logit[j], o);
        }
#pragma unroll
        for (int j = 0; j < KNN; ++j) logit[j] += w_b[j];

        float m = logit[0];
#pragma unroll
        for (int j = 1; j < KNN; ++j) m = fmaxf(m, logit[j]);
        float e[KNN]; float ssum = 0.f;
#pragma unroll
        for (int j = 0; j < KNN; ++j) { e[j] = expf(logit[j] - m); ssum += e[j]; }
        const float inv = 1.f / ssum;

        int ids[KNN];
#pragma unroll
        for (int j = 0; j < KNN; ++j) ids[j] = idx[row*KNN + j];

        float4 acc4 = make_float4(0.f, 0.f, 0.f, 0.f);
#pragma unroll
        for (int j = 0; j < KNN; ++j) {
            const float gj = e[j] * inv;
            const float4 f = *(const float4*)&feats[(size_t)ids[j]*D + lane*4];
            acc4.x = fmaf(gj, f.x, acc4.x);
            acc4.y = fmaf(gj, f.y, acc4.y);
            acc4.z = fmaf(gj, f.z, acc4.z);
            acc4.w = fmaf(gj, f.w, acc4.w);
        }
        *(float4*)&fbar[(size_t)row*D + lane*4] = acc4;
    }
}

// ---------------------------------------------------------------------------
// Fused v-GEMM * q  ->  o-GEMM + residual + LayerNorm:
//   w    = (fbar @ w_v^T) * qbuf          (kept in LDS)
//   out  = LN(w @ w_o^T + query) * gamma + beta
// ---------------------------------------------------------------------------
__global__ __launch_bounds__(256) void gemm_vo(const float* __restrict__ fbar,
                                               const float* __restrict__ w_v,
                                               const float* __restrict__ qbuf,
                                               const float* __restrict__ w_o,
                                               const float* __restrict__ query,
                                               const float* __restrict__ gmm,
                                               const float* __restrict__ bta,
                                               float* __restrict__ out)
{
    __shared__ float a_tile[16][D];
    __shared__ float w_tile[16][D];
    const int r0  = blockIdx.x * 16;
    const int tid = threadIdx.x;

    {
        const float4* A4 = (const float4*)(fbar + (size_t)r0 * D);
        float4* T4 = (float4*)(&a_tile[0][0]);
#pragma unroll
        for (int i = 0; i < 4; ++i) T4[tid + i*256] = A4[tid + i*256];
    }
    __syncthreads();

    const int c = tid;
    float acc[16];
#pragma unroll
    for (int r = 0; r < 16; ++r) acc[r] = 0.f;

    // GEMM 1: fbar @ w_v^T
    {
        const float4* W4 = (const float4*)(w_v + (size_t)c * D);
        for (int k4 = 0; k4 < D/4; ++k4) {
            const float4 w = W4[k4];
#pragma unroll
            for (int r = 0; r < 16; ++r) {
                const float4 a = *(const float4*)&a_tile[r][k4*4];
                acc[r] = fmaf(a.x, w.x, fmaf(a.y, w.y, fmaf(a.z, w.z, fmaf(a.w, w.w, acc[r]))));
            }
        }
    }
    // * qbuf -> w_tile
#pragma unroll
    for (int r = 0; r < 16; ++r)
        w_tile[r][c] = acc[r] * qbuf[(size_t)(r0+r)*D + c];
    __syncthreads();

    // GEMM 2: w_tile @ w_o^T
#pragma unroll
    for (int r = 0; r < 16; ++r) acc[r] = 0.f;
    {
        const float4* W4 = (const float4*)(w_o + (size_t)c * D);
        for (int k4 = 0; k4 < D/4; ++k4) {
            const float4 w = W4[k4];
#pragma unroll
            for (int r = 0; r < 16; ++r) {
                const float4 a = *(const float4*)&w_tile[r][k4*4];
                acc[r] = fmaf(a.x, w.x, fmaf(a.y, w.y, fmaf(a.z, w.z, fmaf(a.w, w.w, acc[r]))));
            }
        }
    }

    // residual into a_tile, then per-row LayerNorm
    __syncthreads();
#pragma unroll
    for (int r = 0; r < 16; ++r)
        a_tile[r][c] = acc[r] + query[(size_t)(r0+r)*D + c];
    __syncthreads();

    const int wave = tid >> 6, lane = tid & 63;
#pragma unroll
    for (int rr = 0; rr < 4; ++rr) {
        const int r = wave*4 + rr;
        const float4 v = *(const float4*)&a_tile[r][lane*4];
        float s  = (v.x + v.y) + (v.z + v.w);
        float s2 = fmaf(v.x, v.x, fmaf(v.y, v.y, fmaf(v.z, v.z, v.w*v.w)));
#pragma unroll
        for (int o = 32; o; o >>= 1) { s += __shfl_xor(s, o); s2 += __shfl_xor(s2, o); }
        const float mu  = s * (1.f/256.f);
        const float var = fmaf(s2, 1.f/256.f, -mu*mu);
        const float rs  = rsqrtf(var + 1e-5f);
        const float4 g = *(const float4*)&gmm[lane*4];
        const float4 b = *(const float4*)&bta[lane*4];
        float4 o4;
        o4.x = (v.x - mu) * rs * g.x + b.x;
        o4.y = (v.y - mu) * rs * g.y + b.y;
        o4.z = (v.z - mu) * rs * g.z + b.z;
        o4.w = (v.w - mu) * rs * g.w + b.w;
        *(float4*)&out[(size_t)(r0+r)*D + lane*4] = o4;
    }
}

// ---------------------------------------------------------------------------
extern "C" void kernel_launch(void* const* d_in, const int* in_sizes, int n_in,
                              void* d_out, int out_size, void* d_ws, size_t ws_size,
                              hipStream_t stream)
{
    const float* query = (const float*)d_in[0];
    const float* qpos  = (const float*)d_in[1];
    const float* feats = (const float*)d_in[2];
    const float* spc   = (const float*)d_in[3];
    const float* w_q   = (const float*)d_in[4];
    const float* w_v   = (const float*)d_in[5];
    const float* w_o   = (const float*)d_in[6];
    const float* w_k   = (const float*)d_in[7];
    const float* w_b   = (const float*)d_in[8];
    const float* gamma = (const float*)d_in[9];
    const float* beta  = (const float*)d_in[10];

    const int Nq = in_sizes[0] / D;   // 2048
    const int N  = in_sizes[2] / D;   // 50000

    char* ws = (char*)d_ws;
    size_t off = 0;
    int* counts = (int*)(ws + off); off += ((size_t)NCELL * 4 + 255) & ~(size_t)255;
    int* starts = (int*)(ws + off); off += ((size_t)(NCELL+1) * 4 + 255) & ~(size_t)255;
    int* cursor = (int*)(ws + off); off += ((size_t)NCELL * 4 + 255) & ~(size_t)255;
    float4* pts = (float4*)(ws + off); off += ((size_t)N * 16 + 255) & ~(size_t)255;
    int* idx = (int*)(ws + off); off += ((size_t)Nq * KNN * 4 + 255) & ~(size_t)255;
    float* qbuf = (float*)(ws + off); off += (size_t)Nq * D * 4;
    float* fbar = (float*)(ws + off); off += (size_t)Nq * D * 4;

    zero_counts<<<NCELL/1024, 256, 0, stream>>>((int4*)counts);
    grid_hist<<<(N + 255)/256, 256, 0, stream>>>(spc, counts, N);
    grid_scan<<<1, 1024, 0, stream>>>(counts, starts, cursor);
    grid_scatter<<<(N + 255)/256, 256, 0, stream>>>(spc, cursor, pts, N);
    knn_grid<<<Nq, 64, 0, stream>>>(qpos, pts, starts, idx);
    gemm_q_gate<<<Nq/16, 256, 0, stream>>>(query, w_q, w_k, w_b, feats, idx, qbuf, fbar);
    gemm_vo<<<Nq/16, 256, 0, stream>>>(fbar, w_v, qbuf, w_o, query, gamma, beta, (float*)d_out);
}

// Round 7
// 78.074 us; speedup vs baseline: 8.0591x; 1.7204x over previous
//
#include <hip/hip_runtime.h>
#include <math.h>

#define D       256
#define KNN     8
#define G       16           // grid cells per axis
#define NCELL   (G*G*G)
#define CS      0.625f       // cell size = 10/16, exactly representable
#define EPS_D2  2e-3f        // margin >> f32 rounding error of reference d2
#define ROWS    8            // rows per GEMM block

typedef unsigned long long u64;

// orderable-float transform: monotonic u32 for any f32 (handles negatives)
__device__ __forceinline__ unsigned enc_f32(float f) {
    unsigned b = __float_as_uint(f);
    return b ^ ((unsigned)(((int)b) >> 31) | 0x80000000u);
}
__device__ __forceinline__ float dec_f32(unsigned t) {
    unsigned m = (unsigned)(((int)t) >> 31);
    return __uint_as_float(t ^ (0x80000000u | ~m));
}
__device__ __forceinline__ u64 mkkey(float d2, int j) {
    return ((u64)enc_f32(d2) << 32) | (u64)(unsigned)j;
}
__device__ __forceinline__ int cell_of(float x) {
    int c = (int)(x * 1.6f);
    return c < 0 ? 0 : (c > G-1 ? G-1 : c);
}

// ---------------------------------------------------------------------------
// Grid build: zero -> histogram -> prefix scan -> scatter (x,y,z,idx packed)
// ---------------------------------------------------------------------------
__global__ __launch_bounds__(256) void zero_counts(int4* __restrict__ c)
{
    c[blockIdx.x * 256 + threadIdx.x] = make_int4(0, 0, 0, 0);
}

__global__ __launch_bounds__(256) void grid_hist(const float* __restrict__ spc,
                                                 int* __restrict__ counts, int N)
{
    const int j = blockIdx.x * 256 + threadIdx.x;
    if (j < N) {
        const int cx = cell_of(spc[3*j+0]), cy = cell_of(spc[3*j+1]), cz = cell_of(spc[3*j+2]);
        atomicAdd(&counts[cx | (cy << 4) | (cz << 8)], 1);
    }
}

__global__ __launch_bounds__(1024) void grid_scan(const int* __restrict__ counts,
                                                  int* __restrict__ starts,
                                                  int* __restrict__ cursor)
{
    __shared__ int part[1024];
    const int t = threadIdx.x;
    const int c0 = counts[4*t+0], c1 = counts[4*t+1], c2 = counts[4*t+2], c3 = counts[4*t+3];
    const int s0 = c0, s1 = s0 + c1, s2 = s1 + c2, s3 = s2 + c3;
    part[t] = s3;
    __syncthreads();
    for (int off = 1; off < 1024; off <<= 1) {
        const int v = (t >= off) ? part[t - off] : 0;
        __syncthreads();
        part[t] += v;
        __syncthreads();
    }
    const int excl = (t > 0) ? part[t-1] : 0;
    starts[4*t+0] = excl;        cursor[4*t+0] = excl;
    starts[4*t+1] = excl + s0;   cursor[4*t+1] = excl + s0;
    starts[4*t+2] = excl + s1;   cursor[4*t+2] = excl + s1;
    starts[4*t+3] = excl + s2;   cursor[4*t+3] = excl + s2;
    if (t == 1023) starts[4096] = excl + s3;
}

__global__ __launch_bounds__(256) void grid_scatter(const float* __restrict__ spc,
                                                    int* __restrict__ cursor,
                                                    float4* __restrict__ pts, int N)
{
    const int j = blockIdx.x * 256 + threadIdx.x;
    if (j < N) {
        const float px = spc[3*j+0], py = spc[3*j+1], pz = spc[3*j+2];
        const int cell = cell_of(px) | (cell_of(py) << 4) | (cell_of(pz) << 8);
        const int pos = atomicAdd(&cursor[cell], 1);
        pts[pos] = make_float4(px, py, pz, __int_as_float(j));
    }
}

// ---------------------------------------------------------------------------
// KNN helpers: per-lane sorted top-8 insert (named regs) + destructive merge
// ---------------------------------------------------------------------------
#define INSERT8(xk)                                                            \
    if ((xk) < k7) {                                                           \
        const bool c0 = (xk) < k0, c1 = (xk) < k1, c2 = (xk) < k2,             \
                   c3 = (xk) < k3, c4 = (xk) < k4, c5 = (xk) < k5,             \
                   c6 = (xk) < k6;                                             \
        k7 = c6 ? k6 : (xk);                                                   \
        k6 = c5 ? k5 : (c6 ? (xk) : k6);                                       \
        k5 = c4 ? k4 : (c5 ? (xk) : k5);                                       \
        k4 = c3 ? k3 : (c4 ? (xk) : k4);                                       \
        k3 = c2 ? k2 : (c3 ? (xk) : k3);                                       \
        k2 = c1 ? k1 : (c2 ? (xk) : k2);                                       \
        k1 = c0 ? k0 : (c1 ? (xk) : k1);                                       \
        k0 = c0 ? (xk) : k0;                                                   \
    }

__device__ __forceinline__ void scan_cell(int cell, const float4* __restrict__ pts,
                                          const int* __restrict__ starts,
                                          float qx, float qy, float qz, float sq,
                                          u64& k0, u64& k1, u64& k2, u64& k3,
                                          u64& k4, u64& k5, u64& k6, u64& k7)
{
    const int st = starts[cell], en = starts[cell+1];
    for (int i = st; i < en; ++i) {
        const float4 p = pts[i];
        const float sp  = __fadd_rn(__fadd_rn(__fmul_rn(p.x,p.x), __fmul_rn(p.y,p.y)),
                                    __fmul_rn(p.z,p.z));
        const float dot = __fmaf_rn(qz, p.z, __fmaf_rn(qy, p.y, __fmul_rn(qx, p.x)));
        const float d2  = __fadd_rn(__fsub_rn(sq, __fmul_rn(2.0f, dot)), sp);
        const u64 xk = mkkey(d2, __float_as_int(p.w));
        INSERT8(xk)
    }
}

__device__ __forceinline__ void wave_merge8(int l, u64& k0, u64& k1, u64& k2, u64& k3,
                                            u64& k4, u64& k5, u64& k6, u64& k7,
                                            u64& mine, u64& worst)
{
#pragma unroll
    for (int rd = 0; rd < KNN; ++rd) {
        u64 m = k0;
#pragma unroll
        for (int o = 32; o; o >>= 1) {
            const u64 t = __shfl_xor(m, o);
            if (t < m) m = t;
        }
        if (k0 == m) {   // owner pops its sorted list
            k0 = k1; k1 = k2; k2 = k3; k3 = k4; k4 = k5; k5 = k6; k6 = k7;
            k7 = ~0ull;
        }
        if (l == rd) mine = m;
        if (rd == KNN-1) worst = m;   // wave-uniform
    }
}

// ---------------------------------------------------------------------------
// KNN: one wave per query, single-shot 4x4x4 cell block (1 cell/lane).
// Query sits in the middle two cells per axis -> min distance to any
// non-domain face >= 1.5*CS (dmin^2 >= 0.88) vs 8-NN d2 ~ 0.12.
// Candidates scored with the BIT-EXACT np/BLAS f32 reference formula; exact
// full-grid fallback kept for the (probability ~0) stop-test failure.
// ---------------------------------------------------------------------------
__global__ __launch_bounds__(64) void knn_grid(const float* __restrict__ qpos,
                                               const float4* __restrict__ pts,
                                               const int* __restrict__ starts,
                                               int* __restrict__ idx_out)
{
    const int q = blockIdx.x;
    const int l = threadIdx.x;
    const float qx = qpos[3*q+0], qy = qpos[3*q+1], qz = qpos[3*q+2];
    const float sq = __fadd_rn(__fadd_rn(__fmul_rn(qx,qx), __fmul_rn(qy,qy)),
                               __fmul_rn(qz,qz));
    const int cx = cell_of(qx), cy = cell_of(qy), cz = cell_of(qz);

    auto bstart = [](int c, float coord) {
        const float f = coord * 1.6f - (float)c;
        int b = c + ((f < 0.5f) ? -2 : -1);
        return b < 0 ? 0 : (b > G-4 ? G-4 : b);
    };
    const int bx = bstart(cx, qx), by = bstart(cy, qy), bz = bstart(cz, qz);

    u64 k0 = ~0ull, k1 = ~0ull, k2 = ~0ull, k3 = ~0ull,
        k4 = ~0ull, k5 = ~0ull, k6 = ~0ull, k7 = ~0ull;

    {
        const int x = bx + (l & 3), y = by + ((l >> 2) & 3), z = bz + (l >> 4);
        scan_cell(x | (y << 4) | (z << 8), pts, starts, qx, qy, qz, sq,
                  k0, k1, k2, k3, k4, k5, k6, k7);
    }

    u64 mine = ~0ull, worst = ~0ull;
    wave_merge8(l, k0, k1, k2, k3, k4, k5, k6, k7, mine, worst);

    const float w8 = dec_f32((unsigned)(worst >> 32));
    float dmin = INFINITY;
    if (bx > 0)     dmin = fminf(dmin, qx - (float)bx * CS);
    if (bx + 4 < G) dmin = fminf(dmin, (float)(bx + 4) * CS - qx);
    if (by > 0)     dmin = fminf(dmin, qy - (float)by * CS);
    if (by + 4 < G) dmin = fminf(dmin, (float)(by + 4) * CS - qy);
    if (bz > 0)     dmin = fminf(dmin, qz - (float)bz * CS);
    if (bz + 4 < G) dmin = fminf(dmin, (float)(bz + 4) * CS - qz);

    if (!(w8 + EPS_D2 <= dmin * dmin)) {
        k0 = (l < KNN) ? mine : ~0ull;
        k1 = ~0ull; k2 = ~0ull; k3 = ~0ull; k4 = ~0ull; k5 = ~0ull; k6 = ~0ull; k7 = ~0ull;
        for (int c = l; c < NCELL; c += 64) {
            const int x = c & 15, y = (c >> 4) & 15, z = c >> 8;
            if (x >= bx && x < bx+4 && y >= by && y < by+4 && z >= bz && z < bz+4) continue;
            scan_cell(c, pts, starts, qx, qy, qz, sq, k0, k1, k2, k3, k4, k5, k6, k7);
        }
        wave_merge8(l, k0, k1, k2, k3, k4, k5, k6, k7, mine, worst);
    }

    if (l < KNN) idx_out[q*KNN + l] = (int)(unsigned)(mine & 0xffffffffu);
}

// ---------------------------------------------------------------------------
// Fused q-GEMM + gate + gather. 8 rows/block, 512 threads, 2-way K-split:
// thread (h = tid>>8, c = tid&255) computes partial dot over K in
// [128h, 128h+128); halves combined through LDS. Epilogue: wave w owns
// row w (gate softmax + weighted feats gather).
// ---------------------------------------------------------------------------
__global__ __launch_bounds__(512) void gemm_q_gate(const float* __restrict__ A,
                                                   const float* __restrict__ W,
                                                   const float* __restrict__ w_k,
                                                   const float* __restrict__ w_b,
                                                   const float* __restrict__ feats,
                                                   const int* __restrict__ idx,
                                                   float* __restrict__ qbuf,
                                                   float* __restrict__ fbar)
{
    __shared__ float a_tile[ROWS][D];
    __shared__ float part[ROWS][D];
    __shared__ float q_tile[ROWS][D];
    const int r0  = blockIdx.x * ROWS;
    const int tid = threadIdx.x;
    const int c = tid & 255, h = tid >> 8;

    ((float4*)&a_tile[0][0])[tid] = ((const float4*)(A + (size_t)r0 * D))[tid];
    __syncthreads();

    float acc[ROWS];
#pragma unroll
    for (int r = 0; r < ROWS; ++r) acc[r] = 0.f;

    const float4* W4 = (const float4*)(W + (size_t)c * D + h * 128);
    for (int k4 = 0; k4 < 32; ++k4) {
        const float4 w = W4[k4];
#pragma unroll
        for (int r = 0; r < ROWS; ++r) {
            const float4 a = *(const float4*)&a_tile[r][h*128 + k4*4];
            acc[r] = fmaf(a.x, w.x, fmaf(a.y, w.y, fmaf(a.z, w.z, fmaf(a.w, w.w, acc[r]))));
        }
    }
    if (h == 1) {
#pragma unroll
        for (int r = 0; r < ROWS; ++r) part[r][c] = acc[r];
    }
    __syncthreads();
    if (h == 0) {
#pragma unroll
        for (int r = 0; r < ROWS; ++r) {
            const float v = acc[r] + part[r][c];
            qbuf[(size_t)(r0+r)*D + c] = v;
            q_tile[r][c] = v;
        }
    }
    __syncthreads();

    // gate epilogue: wave w -> row w
    const int wave = tid >> 6, lane = tid & 63;
    const int row = r0 + wave;
    const float4 qv = *(const float4*)&q_tile[wave][lane*4];

    float logit[KNN];
#pragma unroll
    for (int j = 0; j < KNN; ++j) {
        const float4 w = *(const float4*)&w_k[(size_t)j*D + lane*4];
        logit[j] = fmaf(qv.x, w.x, fmaf(qv.y, w.y, fmaf(qv.z, w.z, qv.w*w.w)));
    }
#pragma unroll
    for (int o = 32; o; o >>= 1) {
#pragma unroll
        for (int j = 0; j < KNN; ++j) logit[j] += __shfl_xor(logit[j], o);
    }
#pragma unroll
    for (int j = 0; j < KNN; ++j) logit[j] += w_b[j];

    float m = logit[0];
#pragma unroll
    for (int j = 1; j < KNN; ++j) m = fmaxf(m, logit[j]);
    float e[KNN]; float ssum = 0.f;
#pragma unroll
    for (int j = 0; j < KNN; ++j) { e[j] = expf(logit[j] - m); ssum += e[j]; }
    const float inv = 1.f / ssum;

    int ids[KNN];
#pragma unroll
    for (int j = 0; j < KNN; ++j) ids[j] = idx[row*KNN + j];

    float4 acc4 = make_float4(0.f, 0.f, 0.f, 0.f);
#pragma unroll
    for (int j = 0; j < KNN; ++j) {
        const float gj = e[j] * inv;
        const float4 f = *(const float4*)&feats[(size_t)ids[j]*D + lane*4];
        acc4.x = fmaf(gj, f.x, acc4.x);
        acc4.y = fmaf(gj, f.y, acc4.y);
        acc4.z = fmaf(gj, f.z, acc4.z);
        acc4.w = fmaf(gj, f.w, acc4.w);
    }
    *(float4*)&fbar[(size_t)row*D + lane*4] = acc4;
}

// ---------------------------------------------------------------------------
// Fused v-GEMM * q -> o-GEMM + residual + LayerNorm. Same 8-row / 512-thread
// 2-way K-split structure; intermediate w stays in LDS; LN wave-per-row.
// ---------------------------------------------------------------------------
__global__ __launch_bounds__(512) void gemm_vo(const float* __restrict__ fbar,
                                               const float* __restrict__ w_v,
                                               const float* __restrict__ qbuf,
                                               const float* __restrict__ w_o,
                                               const float* __restrict__ query,
                                               const float* __restrict__ gmm,
                                               const float* __restrict__ bta,
                                               float* __restrict__ out)
{
    __shared__ float a_tile[ROWS][D];
    __shared__ float part[ROWS][D];
    __shared__ float w_tile[ROWS][D];
    const int r0  = blockIdx.x * ROWS;
    const int tid = threadIdx.x;
    const int c = tid & 255, h = tid >> 8;

    ((float4*)&a_tile[0][0])[tid] = ((const float4*)(fbar + (size_t)r0 * D))[tid];
    __syncthreads();

    float acc[ROWS];
#pragma unroll
    for (int r = 0; r < ROWS; ++r) acc[r] = 0.f;

    // GEMM 1: fbar @ w_v^T (k-split halves)
    {
        const float4* W4 = (const float4*)(w_v + (size_t)c * D + h * 128);
        for (int k4 = 0; k4 < 32; ++k4) {
            const float4 w = W4[k4];
#pragma unroll
            for (int r = 0; r < ROWS; ++r) {
                const float4 a = *(const float4*)&a_tile[r][h*128 + k4*4];
                acc[r] = fmaf(a.x, w.x, fmaf(a.y, w.y, fmaf(a.z, w.z, fmaf(a.w, w.w, acc[r]))));
            }
        }
    }
    if (h == 1) {
#pragma unroll
        for (int r = 0; r < ROWS; ++r) part[r][c] = acc[r];
    }
    __syncthreads();
    if (h == 0) {
#pragma unroll
        for (int r = 0; r < ROWS; ++r)
            w_tile[r][c] = (acc[r] + part[r][c]) * qbuf[(size_t)(r0+r)*D + c];
    }
    __syncthreads();

    // GEMM 2: w_tile @ w_o^T (k-split halves)
#pragma unroll
    for (int r = 0; r < ROWS; ++r) acc[r] = 0.f;
    {
        const float4* W4 = (const float4*)(w_o + (size_t)c * D + h * 128);
        for (int k4 = 0; k4 < 32; ++k4) {
            const float4 w = W4[k4];
#pragma unroll
            for (int r = 0; r < ROWS; ++r) {
                const float4 a = *(const float4*)&w_tile[r][h*128 + k4*4];
                acc[r] = fmaf(a.x, w.x, fmaf(a.y, w.y, fmaf(a.z, w.z, fmaf(a.w, w.w, acc[r]))));
            }
        }
    }
    if (h == 1) {
#pragma unroll
        for (int r = 0; r < ROWS; ++r) part[r][c] = acc[r];
    }
    __syncthreads();
    if (h == 0) {
#pragma unroll
        for (int r = 0; r < ROWS; ++r)
            a_tile[r][c] = acc[r] + part[r][c] + query[(size_t)(r0+r)*D + c];
    }
    __syncthreads();

    // LayerNorm: wave w -> row w
    const int wave = tid >> 6, lane = tid & 63;
    const float4 v = *(const float4*)&a_tile[wave][lane*4];
    float s  = (v.x + v.y) + (v.z + v.w);
    float s2 = fmaf(v.x, v.x, fmaf(v.y, v.y, fmaf(v.z, v.z, v.w*v.w)));
#pragma unroll
    for (int o = 32; o; o >>= 1) { s += __shfl_xor(s, o); s2 += __shfl_xor(s2, o); }
    const float mu  = s * (1.f/256.f);
    const float var = fmaf(s2, 1.f/256.f, -mu*mu);
    const float rs  = rsqrtf(var + 1e-5f);
    const float4 g = *(const float4*)&gmm[lane*4];
    const float4 b = *(const float4*)&bta[lane*4];
    float4 o4;
    o4.x = (v.x - mu) * rs * g.x + b.x;
    o4.y = (v.y - mu) * rs * g.y + b.y;
    o4.z = (v.z - mu) * rs * g.z + b.z;
    o4.w = (v.w - mu) * rs * g.w + b.w;
    *(float4*)&out[(size_t)(r0+wave)*D + lane*4] = o4;
}

// ---------------------------------------------------------------------------
extern "C" void kernel_launch(void* const* d_in, const int* in_sizes, int n_in,
                              void* d_out, int out_size, void* d_ws, size_t ws_size,
                              hipStream_t stream)
{
    const float* query = (const float*)d_in[0];
    const float* qpos  = (const float*)d_in[1];
    const float* feats = (const float*)d_in[2];
    const float* spc   = (const float*)d_in[3];
    const float* w_q   = (const float*)d_in[4];
    const float* w_v   = (const float*)d_in[5];
    const float* w_o   = (const float*)d_in[6];
    const float* w_k   = (const float*)d_in[7];
    const float* w_b   = (const float*)d_in[8];
    const float* gamma = (const float*)d_in[9];
    const float* beta  = (const float*)d_in[10];

    const int Nq = in_sizes[0] / D;   // 2048
    const int N  = in_sizes[2] / D;   // 50000

    char* ws = (char*)d_ws;
    size_t off = 0;
    int* counts = (int*)(ws + off); off += ((size_t)NCELL * 4 + 255) & ~(size_t)255;
    int* starts = (int*)(ws + off); off += ((size_t)(NCELL+1) * 4 + 255) & ~(size_t)255;
    int* cursor = (int*)(ws + off); off += ((size_t)NCELL * 4 + 255) & ~(size_t)255;
    float4* pts = (float4*)(ws + off); off += ((size_t)N * 16 + 255) & ~(size_t)255;
    int* idx = (int*)(ws + off); off += ((size_t)Nq * KNN * 4 + 255) & ~(size_t)255;
    float* qbuf = (float*)(ws + off); off += (size_t)Nq * D * 4;
    float* fbar = (float*)(ws + off); off += (size_t)Nq * D * 4;

    zero_counts<<<NCELL/1024, 256, 0, stream>>>((int4*)counts);
    grid_hist<<<(N + 255)/256, 256, 0, stream>>>(spc, counts, N);
    grid_scan<<<1, 1024, 0, stream>>>(counts, starts, cursor);
    grid_scatter<<<(N + 255)/256, 256, 0, stream>>>(spc, cursor, pts, N);
    knn_grid<<<Nq, 64, 0, stream>>>(qpos, pts, starts, idx);
    gemm_q_gate<<<Nq/ROWS, 512, 0, stream>>>(query, w_q, w_k, w_b, feats, idx, qbuf, fbar);
    gemm_vo<<<Nq/ROWS, 512, 0, stream>>>(fbar, w_v, qbuf, w_o, query, gamma, beta, (float*)d_out);
}

// Round 8
// 67.848 us; speedup vs baseline: 9.2738x; 1.1507x over previous
//
#include <hip/hip_runtime.h>
#include <math.h>

#define D        256
#define KNN      8
#define G        16           // grid cells per axis
#define NCELL    (G*G*G)
#define CS       0.625f       // cell size = 10/16, exactly representable
#define EPS_D2   2e-3f        // margin >> f32 rounding error of reference d2
#define ROWS     8            // rows per fused block
#define CAP      64           // fixed bin capacity (Poisson(12.2); P(>64)~1e-40)
#define SPILLMAX 50000        // spill can hold every point -> never drops

typedef unsigned long long u64;

// orderable-float transform: monotonic u32 for any f32 (handles negatives)
__device__ __forceinline__ unsigned enc_f32(float f) {
    unsigned b = __float_as_uint(f);
    return b ^ ((unsigned)(((int)b) >> 31) | 0x80000000u);
}
__device__ __forceinline__ float dec_f32(unsigned t) {
    unsigned m = (unsigned)(((int)t) >> 31);
    return __uint_as_float(t ^ (0x80000000u | ~m));
}
__device__ __forceinline__ u64 mkkey(float d2, int j) {
    return ((u64)enc_f32(d2) << 32) | (u64)(unsigned)j;
}
__device__ __forceinline__ int cell_of(float x) {
    int c = (int)(x * 1.6f);
    return c < 0 ? 0 : (c > G-1 ? G-1 : c);
}

// ---------------------------------------------------------------------------
// Grid build, bin version: zero (cnt + spill_cnt) then scatter into
// fixed-capacity bins; overflow goes to an exact spill list.
// ---------------------------------------------------------------------------
__global__ __launch_bounds__(256) void zero_bins(int4* __restrict__ cnt4,
                                                 int* __restrict__ spill_cnt)
{
    const int t = blockIdx.x * 256 + threadIdx.x;   // 4 blocks -> t < 1024
    cnt4[t] = make_int4(0, 0, 0, 0);
    if (t == 0) *spill_cnt = 0;
}

__global__ __launch_bounds__(256) void scatter_bins(const float* __restrict__ spc,
                                                    int* __restrict__ cnt,
                                                    float4* __restrict__ bins,
                                                    int* __restrict__ spill_cnt,
                                                    float4* __restrict__ spill, int N)
{
    const int j = blockIdx.x * 256 + threadIdx.x;
    if (j >= N) return;
    const float px = spc[3*j+0], py = spc[3*j+1], pz = spc[3*j+2];
    const int cell = cell_of(px) | (cell_of(py) << 4) | (cell_of(pz) << 8);
    const float4 p = make_float4(px, py, pz, __int_as_float(j));
    const int pos = atomicAdd(&cnt[cell], 1);
    if (pos < CAP) bins[cell*CAP + pos] = p;
    else {
        const int sp = atomicAdd(spill_cnt, 1);
        if (sp < SPILLMAX) spill[sp] = p;
    }
}

// ---------------------------------------------------------------------------
// KNN helpers
// ---------------------------------------------------------------------------
#define INSERT8(xk)                                                            \
    if ((xk) < k7) {                                                           \
        const bool c0 = (xk) < k0, c1 = (xk) < k1, c2 = (xk) < k2,             \
                   c3 = (xk) < k3, c4 = (xk) < k4, c5 = (xk) < k5,             \
                   c6 = (xk) < k6;                                             \
        k7 = c6 ? k6 : (xk);                                                   \
        k6 = c5 ? k5 : (c6 ? (xk) : k6);                                       \
        k5 = c4 ? k4 : (c5 ? (xk) : k5);                                       \
        k4 = c3 ? k3 : (c4 ? (xk) : k4);                                       \
        k3 = c2 ? k2 : (c3 ? (xk) : k3);                                       \
        k2 = c1 ? k1 : (c2 ? (xk) : k2);                                       \
        k1 = c0 ? k0 : (c1 ? (xk) : k1);                                       \
        k0 = c0 ? (xk) : k0;                                                   \
    }

// bit-exact np/BLAS f32 d2: dot = fma(qz,pz, fma(qy,py, fl(qx*px)));
//                           d2  = (sq - fl(2*dot)) + sp
#define SCORE(p)                                                               \
    {                                                                          \
        const float sp  = __fadd_rn(__fadd_rn(__fmul_rn((p).x,(p).x),          \
                                  __fmul_rn((p).y,(p).y)), __fmul_rn((p).z,(p).z)); \
        const float dot = __fmaf_rn(qz,(p).z, __fmaf_rn(qy,(p).y, __fmul_rn(qx,(p).x))); \
        const float d2  = __fadd_rn(__fsub_rn(sq, __fmul_rn(2.0f, dot)), sp);  \
        const u64 xk = mkkey(d2, __float_as_int((p).w));                       \
        INSERT8(xk)                                                            \
    }

__device__ __forceinline__ void scan_cell_bins(int cell, const float4* __restrict__ bins,
                                               const int* __restrict__ cnt,
                                               float qx, float qy, float qz, float sq,
                                               u64& k0, u64& k1, u64& k2, u64& k3,
                                               u64& k4, u64& k5, u64& k6, u64& k7)
{
    const int n = min(cnt[cell], CAP);
    const int st = cell * CAP;
    for (int i = 0; i < n; ++i) {
        const float4 p = bins[st + i];
        SCORE(p)
    }
}

__device__ __forceinline__ void wave_merge8(int l, u64& k0, u64& k1, u64& k2, u64& k3,
                                            u64& k4, u64& k5, u64& k6, u64& k7,
                                            u64& mine, u64& worst)
{
#pragma unroll
    for (int rd = 0; rd < KNN; ++rd) {
        u64 m = k0;
#pragma unroll
        for (int o = 32; o; o >>= 1) {
            const u64 t = __shfl_xor(m, o);
            if (t < m) m = t;
        }
        if (k0 == m) {   // owner pops its sorted list
            k0 = k1; k1 = k2; k2 = k3; k3 = k4; k4 = k5; k5 = k6; k6 = k7;
            k7 = ~0ull;
        }
        if (l == rd) mine = m;
        if (rd == KNN-1) worst = m;   // wave-uniform
    }
}

// ---------------------------------------------------------------------------
// KNN: one wave per query, single-shot 4x4x4 cell block (1 cell/lane) +
// spill-list scan (normally zero-trip). Stop test vs nearest unvisited
// region; exact full-grid fallback (probability ~0).
// ---------------------------------------------------------------------------
__global__ __launch_bounds__(64) void knn_grid(const float* __restrict__ qpos,
                                               const float4* __restrict__ bins,
                                               const int* __restrict__ cnt,
                                               const int* __restrict__ spill_cnt,
                                               const float4* __restrict__ spill,
                                               int* __restrict__ idx_out)
{
    const int q = blockIdx.x;
    const int l = threadIdx.x;
    const float qx = qpos[3*q+0], qy = qpos[3*q+1], qz = qpos[3*q+2];
    const float sq = __fadd_rn(__fadd_rn(__fmul_rn(qx,qx), __fmul_rn(qy,qy)),
                               __fmul_rn(qz,qz));
    const int cx = cell_of(qx), cy = cell_of(qy), cz = cell_of(qz);

    auto bstart = [](int c, float coord) {
        const float f = coord * 1.6f - (float)c;
        int b = c + ((f < 0.5f) ? -2 : -1);
        return b < 0 ? 0 : (b > G-4 ? G-4 : b);
    };
    const int bx = bstart(cx, qx), by = bstart(cy, qy), bz = bstart(cz, qz);

    u64 k0 = ~0ull, k1 = ~0ull, k2 = ~0ull, k3 = ~0ull,
        k4 = ~0ull, k5 = ~0ull, k6 = ~0ull, k7 = ~0ull;

    {   // lane l -> one cell of the 4x4x4 block
        const int x = bx + (l & 3), y = by + ((l >> 2) & 3), z = bz + (l >> 4);
        scan_cell_bins(x | (y << 4) | (z << 8), bins, cnt, qx, qy, qz, sq,
                       k0, k1, k2, k3, k4, k5, k6, k7);
    }
    {   // spill list (exactness; normally empty)
        const int ns = min(*spill_cnt, SPILLMAX);
        for (int i = l; i < ns; i += 64) { const float4 p = spill[i]; SCORE(p) }
    }

    u64 mine = ~0ull, worst = ~0ull;
    wave_merge8(l, k0, k1, k2, k3, k4, k5, k6, k7, mine, worst);

    const float w8 = dec_f32((unsigned)(worst >> 32));   // NaN if <8 cands
    float dmin = INFINITY;
    if (bx > 0)     dmin = fminf(dmin, qx - (float)bx * CS);
    if (bx + 4 < G) dmin = fminf(dmin, (float)(bx + 4) * CS - qx);
    if (by > 0)     dmin = fminf(dmin, qy - (float)by * CS);
    if (by + 4 < G) dmin = fminf(dmin, (float)(by + 4) * CS - qy);
    if (bz > 0)     dmin = fminf(dmin, qz - (float)bz * CS);
    if (bz + 4 < G) dmin = fminf(dmin, (float)(bz + 4) * CS - qz);

    if (!(w8 + EPS_D2 <= dmin * dmin)) {
        // exact fallback: scan every cell outside the block, re-merge
        k0 = (l < KNN) ? mine : ~0ull;
        k1 = ~0ull; k2 = ~0ull; k3 = ~0ull; k4 = ~0ull; k5 = ~0ull; k6 = ~0ull; k7 = ~0ull;
        for (int c = l; c < NCELL; c += 64) {
            const int x = c & 15, y = (c >> 4) & 15, z = c >> 8;
            if (x >= bx && x < bx+4 && y >= by && y < by+4 && z >= bz && z < bz+4) continue;
            scan_cell_bins(c, bins, cnt, qx, qy, qz, sq, k0, k1, k2, k3, k4, k5, k6, k7);
        }
        wave_merge8(l, k0, k1, k2, k3, k4, k5, k6, k7, mine, worst);
    }

    if (l < KNN) idx_out[q*KNN + l] = (int)(unsigned)(mine & 0xffffffffu);
}

// ---------------------------------------------------------------------------
// Fused main: for an 8-row tile, entirely in one block (1024 thr, 16 waves):
//   q    = query @ w_q^T                    (4-way K-split, LDS partials)
//   gate = softmax(q @ w_k^T + w_b)         (wave w -> row w)
//   fbar = sum_j gate_j * feats[idx_j]
//   w    = (fbar @ w_v^T) * q
//   out  = LN(w @ w_o^T + query) * gamma + beta
// All intermediates live in LDS; no global round-trips.
// ---------------------------------------------------------------------------
__global__ __launch_bounds__(1024) void fused_main(const float* __restrict__ query,
                                                   const float* __restrict__ w_q,
                                                   const float* __restrict__ w_k,
                                                   const float* __restrict__ w_b,
                                                   const float* __restrict__ feats,
                                                   const int* __restrict__ idx,
                                                   const float* __restrict__ w_v,
                                                   const float* __restrict__ w_o,
                                                   const float* __restrict__ gmm,
                                                   const float* __restrict__ bta,
                                                   float* __restrict__ out)
{
    __shared__ float a_tile[ROWS][D];       // query rows (kept for residual)
    __shared__ float part[3][ROWS][D];      // K-split partials
    __shared__ float q_tile[ROWS][D];
    __shared__ float f_tile[ROWS][D];       // fbar
    __shared__ float w_tile[ROWS][D];

    const int r0  = blockIdx.x * ROWS;
    const int tid = threadIdx.x;
    const int c = tid & 255, h = tid >> 8;           // h in 0..3, wave-uniform
    const int wave = tid >> 6, lane = tid & 63;

    if (tid < 512)
        ((float4*)&a_tile[0][0])[tid] = ((const float4*)(query + (size_t)r0 * D))[tid];
    __syncthreads();

    float acc[ROWS];

    // ---- GEMM 1: q = query @ w_q^T (K-split quarter h) ----
#pragma unroll
    for (int r = 0; r < ROWS; ++r) acc[r] = 0.f;
    {
        const float4* W4 = (const float4*)(w_q + (size_t)c * D + h * 64);
        for (int k4 = 0; k4 < 16; ++k4) {
            const float4 w = W4[k4];
#pragma unroll
            for (int r = 0; r < ROWS; ++r) {
                const float4 a = *(const float4*)&a_tile[r][h*64 + k4*4];
                acc[r] = fmaf(a.x, w.x, fmaf(a.y, w.y, fmaf(a.z, w.z, fmaf(a.w, w.w, acc[r]))));
            }
        }
    }
    if (h) {
#pragma unroll
        for (int r = 0; r < ROWS; ++r) part[h-1][r][c] = acc[r];
    }
    __syncthreads();
    if (h == 0) {
#pragma unroll
        for (int r = 0; r < ROWS; ++r)
            q_tile[r][c] = acc[r] + part[0][r][c] + part[1][r][c] + part[2][r][c];
    }
    __syncthreads();

    // ---- gate + gather: wave w -> row w (waves 8..15 pass through) ----
    if (wave < ROWS) {
        const int row = r0 + wave;
        const float4 qv = *(const float4*)&q_tile[wave][lane*4];

        float logit[KNN];
#pragma unroll
        for (int j = 0; j < KNN; ++j) {
            const float4 w = *(const float4*)&w_k[(size_t)j*D + lane*4];
            logit[j] = fmaf(qv.x, w.x, fmaf(qv.y, w.y, fmaf(qv.z, w.z, qv.w*w.w)));
        }
#pragma unroll
        for (int o = 32; o; o >>= 1) {
#pragma unroll
            for (int j = 0; j < KNN; ++j) logit[j] += __shfl_xor(logit[j], o);
        }
#pragma unroll
        for (int j = 0; j < KNN; ++j) logit[j] += w_b[j];

        float m = logit[0];
#pragma unroll
        for (int j = 1; j < KNN; ++j) m = fmaxf(m, logit[j]);
        float e[KNN]; float ssum = 0.f;
#pragma unroll
        for (int j = 0; j < KNN; ++j) { e[j] = expf(logit[j] - m); ssum += e[j]; }
        const float inv = 1.f / ssum;

        int ids[KNN];
#pragma unroll
        for (int j = 0; j < KNN; ++j) ids[j] = idx[row*KNN + j];

        float4 acc4 = make_float4(0.f, 0.f, 0.f, 0.f);
#pragma unroll
        for (int j = 0; j < KNN; ++j) {
            const float gj = e[j] * inv;
            const float4 f = *(const float4*)&feats[(size_t)ids[j]*D + lane*4];
            acc4.x = fmaf(gj, f.x, acc4.x);
            acc4.y = fmaf(gj, f.y, acc4.y);
            acc4.z = fmaf(gj, f.z, acc4.z);
            acc4.w = fmaf(gj, f.w, acc4.w);
        }
        *(float4*)&f_tile[wave][lane*4] = acc4;
    }
    __syncthreads();

    // ---- GEMM 2: w = (fbar @ w_v^T) * q ----
#pragma unroll
    for (int r = 0; r < ROWS; ++r) acc[r] = 0.f;
    {
        const float4* W4 = (const float4*)(w_v + (size_t)c * D + h * 64);
        for (int k4 = 0; k4 < 16; ++k4) {
            const float4 w = W4[k4];
#pragma unroll
            for (int r = 0; r < ROWS; ++r) {
                const float4 a = *(const float4*)&f_tile[r][h*64 + k4*4];
                acc[r] = fmaf(a.x, w.x, fmaf(a.y, w.y, fmaf(a.z, w.z, fmaf(a.w, w.w, acc[r]))));
            }
        }
    }
    if (h) {
#pragma unroll
        for (int r = 0; r < ROWS; ++r) part[h-1][r][c] = acc[r];
    }
    __syncthreads();
    if (h == 0) {
#pragma unroll
        for (int r = 0; r < ROWS; ++r)
            w_tile[r][c] = (acc[r] + part[0][r][c] + part[1][r][c] + part[2][r][c])
                           * q_tile[r][c];
    }
    __syncthreads();

    // ---- GEMM 3: out_pre = w @ w_o^T + query ----
#pragma unroll
    for (int r = 0; r < ROWS; ++r) acc[r] = 0.f;
    {
        const float4* W4 = (const float4*)(w_o + (size_t)c * D + h * 64);
        for (int k4 = 0; k4 < 16; ++k4) {
            const float4 w = W4[k4];
#pragma unroll
            for (int r = 0; r < ROWS; ++r) {
                const float4 a = *(const float4*)&w_tile[r][h*64 + k4*4];
                acc[r] = fmaf(a.x, w.x, fmaf(a.y, w.y, fmaf(a.z, w.z, fmaf(a.w, w.w, acc[r]))));
            }
        }
    }
    if (h) {
#pragma unroll
        for (int r = 0; r < ROWS; ++r) part[h-1][r][c] = acc[r];
    }
    __syncthreads();
    if (h == 0) {
#pragma unroll
        for (int r = 0; r < ROWS; ++r)
            a_tile[r][c] = acc[r] + part[0][r][c] + part[1][r][c] + part[2][r][c]
                           + a_tile[r][c];     // residual (a_tile still holds query)
    }
    __syncthreads();

    // ---- LayerNorm: wave w -> row w ----
    if (wave < ROWS) {
        const float4 v = *(const float4*)&a_tile[wave][lane*4];
        float s  = (v.x + v.y) + (v.z + v.w);
        float s2 = fmaf(v.x, v.x, fmaf(v.y, v.y, fmaf(v.z, v.z, v.w*v.w)));
#pragma unroll
        for (int o = 32; o; o >>= 1) { s += __shfl_xor(s, o); s2 += __shfl_xor(s2, o); }
        const float mu  = s * (1.f/256.f);
        const float var = fmaf(s2, 1.f/256.f, -mu*mu);
        const float rs  = rsqrtf(var + 1e-5f);
        const float4 g = *(const float4*)&gmm[lane*4];
        const float4 b = *(const float4*)&bta[lane*4];
        float4 o4;
        o4.x = (v.x - mu) * rs * g.x + b.x;
        o4.y = (v.y - mu) * rs * g.y + b.y;
        o4.z = (v.z - mu) * rs * g.z + b.z;
        o4.w = (v.w - mu) * rs * g.w + b.w;
        *(float4*)&out[(size_t)(r0+wave)*D + lane*4] = o4;
    }
}

// ---------------------------------------------------------------------------
extern "C" void kernel_launch(void* const* d_in, const int* in_sizes, int n_in,
                              void* d_out, int out_size, void* d_ws, size_t ws_size,
                              hipStream_t stream)
{
    const float* query = (const float*)d_in[0];
    const float* qpos  = (const float*)d_in[1];
    const float* feats = (const float*)d_in[2];
    const float* spc   = (const float*)d_in[3];
    const float* w_q   = (const float*)d_in[4];
    const float* w_v   = (const float*)d_in[5];
    const float* w_o   = (const float*)d_in[6];
    const float* w_k   = (const float*)d_in[7];
    const float* w_b   = (const float*)d_in[8];
    const float* gamma = (const float*)d_in[9];
    const float* beta  = (const float*)d_in[10];

    const int Nq = in_sizes[0] / D;   // 2048
    const int N  = in_sizes[2] / D;   // 50000

    char* ws = (char*)d_ws;
    size_t off = 0;
    int* cnt = (int*)(ws + off);          off += ((size_t)NCELL * 4 + 255) & ~(size_t)255;
    int* spill_cnt = (int*)(ws + off);    off += 256;
    float4* bins = (float4*)(ws + off);   off += ((size_t)NCELL * CAP * 16 + 255) & ~(size_t)255;
    float4* spill = (float4*)(ws + off);  off += ((size_t)SPILLMAX * 16 + 255) & ~(size_t)255;
    int* idx = (int*)(ws + off);          off += ((size_t)Nq * KNN * 4 + 255) & ~(size_t)255;

    zero_bins<<<4, 256, 0, stream>>>((int4*)cnt, spill_cnt);
    scatter_bins<<<(N + 255)/256, 256, 0, stream>>>(spc, cnt, bins, spill_cnt, spill, N);
    knn_grid<<<Nq, 64, 0, stream>>>(qpos, bins, cnt, spill_cnt, spill, idx);
    fused_main<<<Nq/ROWS, 1024, 0, stream>>>(query, w_q, w_k, w_b, feats, idx,
                                             w_v, w_o, gamma, beta, (float*)d_out);
}